// Round 12
// baseline (905.855 us; speedup 1.0000x reference)
//
#include <hip/hip_runtime.h>
#include <hip/hip_bf16.h>

#define N_NODES 100000
#define N_EDGES 3200000
#define HID 16
#define NB 256       // buckets; bucket = NPB consecutive nodes
#define NPB 391      // 256*391 = 100096 >= 100000
#define SCAP 15360   // per-bucket staging cap (mean 12500, +25 sigma)
#define RCAP 15360
#define FDEPTH 32    // LDS FIFO depth in split kernels
#define LCAP1 8704   // bsort1 LDS chunk entries (12 B) -> ~102 KB
#define LCAP2 26624  // rsort LDS chunk entries (4 B) -> 104 KB (1 chunk/bucket)

static constexpr int BLK = 256;

typedef __attribute__((ext_vector_type(8))) short bf16x8;
typedef __attribute__((ext_vector_type(4))) float f32x4;

__device__ __forceinline__ float frelu(float x) { return fmaxf(x, 0.f); }
__device__ __forceinline__ float bflo(unsigned int u) {
  return __uint_as_float(u << 16);
}
__device__ __forceinline__ float bfhi(unsigned int u) {
  return __uint_as_float(u & 0xFFFF0000u);
}
__device__ __forceinline__ unsigned int packbf(float lo, float hi) {
  __hip_bfloat16 hl = __float2bfloat16(lo), hh = __float2bfloat16(hi);
  return ((unsigned int)(*(unsigned short*)&hh) << 16) |
         (unsigned int)(*(unsigned short*)&hl);
}
__device__ __forceinline__ short f2bs(float v) {
  __hip_bfloat16 hb = __float2bfloat16(v);
  return *(short*)&hb;
}

union E16 {
  float4 f4[2];
  __hip_bfloat16 h[16];
};

// ---------------------------------------------------------------------------
// K0: norm = max |edges_init|
// ---------------------------------------------------------------------------
__global__ __launch_bounds__(256) void k_norm(const float* __restrict__ edges,
                                              unsigned int* __restrict__ normbits) {
  float m = 0.f;
  for (int i = blockIdx.x * blockDim.x + threadIdx.x; i < N_EDGES;
       i += gridDim.x * blockDim.x)
    m = fmaxf(m, fabsf(edges[i]));
#pragma unroll
  for (int off = 32; off > 0; off >>= 1)
    m = fmaxf(m, __shfl_down(m, off, 64));
  __shared__ float smax[BLK / 64];
  if ((threadIdx.x & 63) == 0) smax[threadIdx.x >> 6] = m;
  __syncthreads();
  if (threadIdx.x == 0) {
    float b = smax[0];
#pragma unroll
    for (int w = 1; w < BLK / 64; ++w) b = fmaxf(b, smax[w]);
    atomicMax(normbits, __float_as_uint(b));
  }
}

// ---------------------------------------------------------------------------
// K1: bucket edges by SENDER via LDS FIFOs (line-granular flushes).
// record: m = (sender_local<<22) | orig_edge(22b), v = edges_init, o = recv
// ---------------------------------------------------------------------------
__global__ __launch_bounds__(1024) void k_split(
    const int* __restrict__ senders, const int* __restrict__ receivers,
    const float* __restrict__ edges, int* __restrict__ gcnt,
    unsigned int* __restrict__ pM, float* __restrict__ pV,
    unsigned int* __restrict__ pO) {
  __shared__ __align__(16) unsigned int fM[NB][FDEPTH];
  __shared__ __align__(16) unsigned int fV[NB][FDEPTH];
  __shared__ __align__(16) unsigned int fO[NB][FDEPTH];
  __shared__ int fcnt[NB];
  const int t = threadIdx.x;
  if (t < NB) fcnt[t] = 0;
  __syncthreads();
  const int e0 = blockIdx.x * (N_EDGES / 256);
  const int e1 = e0 + (N_EDGES / 256);
  for (int base = e0; base < e1; base += 1024) {
    const int i = base + t;
    if (i < e1) {
      int s = senders[i];
      unsigned int b = (unsigned int)s / NPB;
      unsigned int m = (((unsigned int)s - b * NPB) << 22) | (unsigned int)i;
      unsigned int v = __float_as_uint(edges[i]);
      unsigned int o = (unsigned int)receivers[i];
      int pos = atomicAdd(&fcnt[b], 1);
      if (pos < FDEPTH) {
        fM[b][pos] = m; fV[b][pos] = v; fO[b][pos] = o;
      } else {  // rare overflow: direct append
        int gb = atomicAdd(&gcnt[b], 1);
        if (gb < SCAP) {
          pM[(size_t)b * SCAP + gb] = m;
          pV[(size_t)b * SCAP + gb] = __uint_as_float(v);
          pO[(size_t)b * SCAP + gb] = o;
        }
      }
    }
    __syncthreads();
    const bool last = (base + 1024 >= e1);
    if (t < NB) {
      int c = fcnt[t]; if (c > FDEPTH) c = FDEPTH;
      int nf = last ? c : (c & ~15);
      if (nf > 0) {
        int gb = atomicAdd(&gcnt[t], nf);
        size_t db = (size_t)t * SCAP + gb;
        if ((gb & 3) == 0 && gb + nf <= SCAP) {
          int k = 0;
          for (; k + 4 <= nf; k += 4) {
            *(uint4*)(pM + db + k) = *(const uint4*)(&fM[t][k]);
            *(uint4*)((unsigned int*)pV + db + k) = *(const uint4*)(&fV[t][k]);
            *(uint4*)(pO + db + k) = *(const uint4*)(&fO[t][k]);
          }
          for (; k < nf; ++k) {
            pM[db + k] = fM[t][k]; pV[db + k] = __uint_as_float(fV[t][k]);
            pO[db + k] = fO[t][k];
          }
        } else {
          for (int k = 0; k < nf; ++k)
            if (gb + k < SCAP) {
              pM[db + k] = fM[t][k]; pV[db + k] = __uint_as_float(fV[t][k]);
              pO[db + k] = fO[t][k];
            }
        }
        int res = c - nf;
        for (int k = 0; k < res; ++k) {
          fM[t][k] = fM[t][nf + k]; fV[t][k] = fV[t][nf + k];
          fO[t][k] = fO[t][nf + k];
        }
        fcnt[t] = res;
      } else fcnt[t] = c;
    }
    __syncthreads();
  }
}

// ---------------------------------------------------------------------------
// K2: per-bucket counting sort by sender_local -> EXACT global sender CSR.
// Writes srecv/sorig/svalbf/ssend32 (global sender id) + soff.
// ---------------------------------------------------------------------------
__global__ __launch_bounds__(1024) void k_bsort1(
    const unsigned int* __restrict__ pM, const float* __restrict__ pV,
    const unsigned int* __restrict__ pO, const int* __restrict__ gcnt,
    unsigned int* __restrict__ srecv, unsigned int* __restrict__ sorig,
    unsigned short* __restrict__ svalbf, unsigned int* __restrict__ ssend32,
    int* __restrict__ soff) {
  __shared__ unsigned int sM[LCAP1];
  __shared__ float sV[LCAP1];
  __shared__ unsigned int sO[LCAP1];
  __shared__ int hist[NPB], pref[NPB + 1], sc[NPB], cur[NPB];
  __shared__ int bb[NB];
  __shared__ int base_s;
  const int b = blockIdx.x, t = threadIdx.x, nt = blockDim.x;
  if (t < NB) { int c = gcnt[t]; bb[t] = c > SCAP ? SCAP : c; }
  for (int k = t; k < NPB; k += nt) hist[k] = 0;
  __syncthreads();
  if (t == 0) { int s = 0; for (int k = 0; k < b; ++k) s += bb[k]; base_s = s; }
  int nb = gcnt[b]; if (nb > SCAP) nb = SCAP;
  const unsigned int* PM = pM + (size_t)b * SCAP;
  const float* PV = pV + (size_t)b * SCAP;
  const unsigned int* PO = pO + (size_t)b * SCAP;
  for (int i = t; i < nb; i += nt) atomicAdd(&hist[PM[i] >> 22], 1);
  __syncthreads();
  if (t < NPB) sc[t] = hist[t];
  __syncthreads();
  for (int d = 1; d < NPB; d <<= 1) {
    int add = 0;
    if (t < NPB && t >= d) add = sc[t - d];
    __syncthreads();
    if (t < NPB && t >= d) sc[t] += add;
    __syncthreads();
  }
  if (t < NPB) pref[t] = sc[t] - hist[t];
  if (t == 0) pref[NPB] = sc[NPB - 1];
  __syncthreads();
  const int base = base_s;
  const int node0 = b * NPB;
  for (int k = t; k < NPB; k += nt) {
    int n = node0 + k;
    if (n < N_NODES) soff[n] = base + pref[k];
  }
  if (b == NB - 1 && t == 0) soff[N_NODES] = base + nb;
  __syncthreads();
  int klo = 0;
  while (klo < NPB) {
    int base0 = pref[klo];
    int khi = klo;
    while (khi < NPB && pref[khi + 1] - base0 <= LCAP1) ++khi;
    if (khi == klo) khi = klo + 1;  // safety
    for (int k = klo + t; k < khi; k += nt) cur[k] = pref[k];
    __syncthreads();
    for (int i = t; i < nb; i += nt) {
      unsigned int m = PM[i];
      int key = (int)(m >> 22);
      if (key >= klo && key < khi) {
        int p = atomicAdd(&cur[key], 1) - base0;
        if (p < LCAP1) { sM[p] = m; sV[p] = PV[i]; sO[p] = PO[i]; }
      }
    }
    __syncthreads();
    int csz = pref[khi] - base0;
    for (int i = t; i < csz; i += nt) {
      int g = base + base0 + i;
      unsigned int m = sM[i];
      srecv[g] = sO[i]; sorig[g] = m & 0x3FFFFFu;
      ssend32[g] = (unsigned int)(node0 + (int)(m >> 22));
      __hip_bfloat16 hb = __float2bfloat16(sV[i]);
      svalbf[g] = *(unsigned short*)&hb;
    }
    __syncthreads();
    klo = khi;
  }
}

// ---------------------------------------------------------------------------
// K3: bucket sorted edges by RECEIVER. a = (recv_local<<22) | sorted_idx
// ---------------------------------------------------------------------------
__global__ __launch_bounds__(1024) void k_rsplit(
    const unsigned int* __restrict__ srecv, int* __restrict__ gcnt2,
    unsigned int* __restrict__ rpA) {
  __shared__ __align__(16) unsigned int fA[NB][FDEPTH];
  __shared__ int fcnt[NB];
  const int t = threadIdx.x;
  if (t < NB) fcnt[t] = 0;
  __syncthreads();
  const int e0 = blockIdx.x * (N_EDGES / 256);
  const int e1 = e0 + (N_EDGES / 256);
  for (int base = e0; base < e1; base += 1024) {
    const int i = base + t;
    if (i < e1) {
      unsigned int r = srecv[i];
      unsigned int b = r / NPB;
      unsigned int a = ((r - b * NPB) << 22) | (unsigned int)i;
      int pos = atomicAdd(&fcnt[b], 1);
      if (pos < FDEPTH) {
        fA[b][pos] = a;
      } else {
        int gb = atomicAdd(&gcnt2[b], 1);
        if (gb < RCAP) rpA[(size_t)b * RCAP + gb] = a;
      }
    }
    __syncthreads();
    const bool last = (base + 1024 >= e1);
    if (t < NB) {
      int c = fcnt[t]; if (c > FDEPTH) c = FDEPTH;
      int nf = last ? c : (c & ~15);
      if (nf > 0) {
        int gb = atomicAdd(&gcnt2[t], nf);
        size_t db = (size_t)t * RCAP + gb;
        if ((gb & 3) == 0 && gb + nf <= RCAP) {
          int k = 0;
          for (; k + 4 <= nf; k += 4)
            *(uint4*)(rpA + db + k) = *(const uint4*)(&fA[t][k]);
          for (; k < nf; ++k) rpA[db + k] = fA[t][k];
        } else {
          for (int k = 0; k < nf; ++k)
            if (gb + k < RCAP) rpA[db + k] = fA[t][k];
        }
        int res = c - nf;
        for (int k = 0; k < res; ++k) fA[t][k] = fA[t][nf + k];
        fcnt[t] = res;
      } else fcnt[t] = c;
    }
    __syncthreads();
  }
}

// ---------------------------------------------------------------------------
// K4: per-bucket counting sort by recv_local -> receiver CSR (roff) + rlist.
// ---------------------------------------------------------------------------
__global__ __launch_bounds__(1024) void k_rsort(
    const unsigned int* __restrict__ rpA, const int* __restrict__ gcnt2,
    unsigned int* __restrict__ rlist, int* __restrict__ roff) {
  __shared__ unsigned int sA[LCAP2];
  __shared__ int hist[NPB], pref[NPB + 1], sc[NPB], cur[NPB];
  __shared__ int bb[NB];
  __shared__ int base_s;
  const int b = blockIdx.x, t = threadIdx.x, nt = blockDim.x;
  if (t < NB) { int c = gcnt2[t]; bb[t] = c > RCAP ? RCAP : c; }
  for (int k = t; k < NPB; k += nt) hist[k] = 0;
  __syncthreads();
  if (t == 0) { int s = 0; for (int k = 0; k < b; ++k) s += bb[k]; base_s = s; }
  int nb = gcnt2[b]; if (nb > RCAP) nb = RCAP;
  const unsigned int* PA = rpA + (size_t)b * RCAP;
  for (int i = t; i < nb; i += nt) atomicAdd(&hist[PA[i] >> 22], 1);
  __syncthreads();
  if (t < NPB) sc[t] = hist[t];
  __syncthreads();
  for (int d = 1; d < NPB; d <<= 1) {
    int add = 0;
    if (t < NPB && t >= d) add = sc[t - d];
    __syncthreads();
    if (t < NPB && t >= d) sc[t] += add;
    __syncthreads();
  }
  if (t < NPB) pref[t] = sc[t] - hist[t];
  if (t == 0) pref[NPB] = sc[NPB - 1];
  __syncthreads();
  const int base = base_s;
  const int node0 = b * NPB;
  for (int k = t; k < NPB; k += nt) {
    int n = node0 + k;
    if (n < N_NODES) roff[n] = base + pref[k];
  }
  if (b == NB - 1 && t == 0) roff[N_NODES] = base + nb;
  __syncthreads();
  int klo = 0;
  while (klo < NPB) {
    int base0 = pref[klo];
    int khi = klo;
    while (khi < NPB && pref[khi + 1] - base0 <= LCAP2) ++khi;
    if (khi == klo) khi = klo + 1;
    for (int k = klo + t; k < khi; k += nt) cur[k] = pref[k];
    __syncthreads();
    for (int i = t; i < nb; i += nt) {
      unsigned int a = PA[i];
      int key = (int)(a >> 22);
      if (key >= klo && key < khi) {
        int p = atomicAdd(&cur[key], 1) - base0;
        if (p < LCAP2) sA[p] = a;
      }
    }
    __syncthreads();
    int csz = pref[khi] - base0;
    for (int i = t; i < csz; i += nt)
      rlist[base + base0 + i] = sA[i] & 0x3FFFFFu;
    __syncthreads();
    klo = khi;
  }
}

// ---------------------------------------------------------------------------
// K5: edge encoder (1 -> HID -> HID) in sorted order, coalesced.
// ---------------------------------------------------------------------------
__global__ __launch_bounds__(256) void k_encode(
    const unsigned short* __restrict__ svalbf, const float* __restrict__ w1,
    const float* __restrict__ b1, const float* __restrict__ w2,
    const float* __restrict__ b2, const unsigned int* __restrict__ normbits,
    unsigned short* __restrict__ e) {
  int i = blockIdx.x * blockDim.x + threadIdx.x;
  float norm = __uint_as_float(*normbits);
  float x = bflo((unsigned int)svalbf[i]) / norm;
  float h[HID];
#pragma unroll
  for (int j = 0; j < HID; ++j) h[j] = frelu(fmaf(w1[j], x, b1[j]));
  E16 o;
#pragma unroll
  for (int j = 0; j < HID; ++j) {
    float acc = b2[j];
#pragma unroll
    for (int k = 0; k < HID; ++k) acc = fmaf(w2[j * HID + k], h[k], acc);
    o.h[j] = __float2bfloat16(acc);
  }
  float4* ep = (float4*)(e + (size_t)i * HID);
  ep[0] = o.f4[0];
  ep[1] = o.f4[1];
}

// ---------------------------------------------------------------------------
// K6: FUSED receiver-gather + sender-stream + node MLP (round-11 form).
// ---------------------------------------------------------------------------
__global__ __launch_bounds__(256) void k_aggN(
    const unsigned short* __restrict__ e, const int* __restrict__ roff,
    const unsigned int* __restrict__ rlist, const int* __restrict__ soff,
    const float* __restrict__ nodesr, const float* __restrict__ nw1,
    const float* __restrict__ nb1_, const float* __restrict__ nw2,
    const float* __restrict__ nb2_, float* __restrict__ nodesw) {
  int wave = (blockIdx.x * blockDim.x + threadIdx.x) >> 6;
  int lane = threadIdx.x & 63, half = lane >> 5, l32 = lane & 31;
  int n = wave * 2 + half;
  // ---- phase A: receiver-side scattered gather (x2 unrolled) ----
  int sub = l32 & 1, j16 = l32 >> 1;
  int r0 = roff[n], rdeg = roff[n + 1] - r0;
  float ar[8] = {0, 0, 0, 0, 0, 0, 0, 0};
  int q0 = 0;
  int full2 = rdeg & ~31;
  for (; q0 < full2; q0 += 32) {
    int idx0 = r0 + q0 + j16;
    unsigned int si0 = rlist[idx0];
    unsigned int si1 = rlist[idx0 + 16];
    uint4 ra = *(const uint4*)(e + (size_t)si0 * HID + sub * 8);
    uint4 rb = *(const uint4*)(e + (size_t)si1 * HID + sub * 8);
    ar[0] += bflo(ra.x); ar[1] += bfhi(ra.x);
    ar[2] += bflo(ra.y); ar[3] += bfhi(ra.y);
    ar[4] += bflo(ra.z); ar[5] += bfhi(ra.z);
    ar[6] += bflo(ra.w); ar[7] += bfhi(ra.w);
    ar[0] += bflo(rb.x); ar[1] += bfhi(rb.x);
    ar[2] += bflo(rb.y); ar[3] += bfhi(rb.y);
    ar[4] += bflo(rb.z); ar[5] += bfhi(rb.z);
    ar[6] += bflo(rb.w); ar[7] += bfhi(rb.w);
  }
  if (q0 + 16 <= rdeg) {
    int idx = r0 + q0 + j16;
    unsigned int si = rlist[idx];
    uint4 raw = *(const uint4*)(e + (size_t)si * HID + sub * 8);
    ar[0] += bflo(raw.x); ar[1] += bfhi(raw.x);
    ar[2] += bflo(raw.y); ar[3] += bfhi(raw.y);
    ar[4] += bflo(raw.z); ar[5] += bfhi(raw.z);
    ar[6] += bflo(raw.w); ar[7] += bfhi(raw.w);
    q0 += 16;
  }
  if (q0 < rdeg) {
    int slot = q0 + j16;
    bool ok = slot < rdeg;
    int idx = r0 + (ok ? slot : 0);
    unsigned int si = rlist[idx];
    uint4 raw = *(const uint4*)(e + (size_t)si * HID + sub * 8);
    float okf = ok ? 1.f : 0.f;
    ar[0] = fmaf(bflo(raw.x), okf, ar[0]); ar[1] = fmaf(bfhi(raw.x), okf, ar[1]);
    ar[2] = fmaf(bflo(raw.y), okf, ar[2]); ar[3] = fmaf(bfhi(raw.y), okf, ar[3]);
    ar[4] = fmaf(bflo(raw.z), okf, ar[4]); ar[5] = fmaf(bfhi(raw.z), okf, ar[5]);
    ar[6] = fmaf(bflo(raw.w), okf, ar[6]); ar[7] = fmaf(bfhi(raw.w), okf, ar[7]);
  }
#pragma unroll
  for (int off = 16; off >= 2; off >>= 1)
#pragma unroll
    for (int c = 0; c < 8; ++c) ar[c] += __shfl_down(ar[c], off, 64);
  // ---- phase B: sender-side coalesced stream ----
  int s0 = soff[n], sdeg = soff[n + 1] - s0;
  float as[16];
#pragma unroll
  for (int c = 0; c < 16; ++c) as[c] = 0.f;
  int fullB = sdeg & ~31;
  int c0 = 0;
  for (; c0 < fullB; c0 += 32) {
    int idx = s0 + c0 + l32;
    uint4 ra = *(const uint4*)(e + (size_t)idx * HID);
    uint4 rb = *(const uint4*)(e + (size_t)idx * HID + 8);
    as[0] += bflo(ra.x);  as[1] += bfhi(ra.x);
    as[2] += bflo(ra.y);  as[3] += bfhi(ra.y);
    as[4] += bflo(ra.z);  as[5] += bfhi(ra.z);
    as[6] += bflo(ra.w);  as[7] += bfhi(ra.w);
    as[8] += bflo(rb.x);  as[9] += bfhi(rb.x);
    as[10] += bflo(rb.y); as[11] += bfhi(rb.y);
    as[12] += bflo(rb.z); as[13] += bfhi(rb.z);
    as[14] += bflo(rb.w); as[15] += bfhi(rb.w);
  }
  if (c0 < sdeg) {
    int k = c0 + l32;
    bool ok = k < sdeg;
    int idx = s0 + (ok ? k : 0);
    uint4 ra = *(const uint4*)(e + (size_t)idx * HID);
    uint4 rb = *(const uint4*)(e + (size_t)idx * HID + 8);
    float okf = ok ? 1.f : 0.f;
    as[0] = fmaf(bflo(ra.x), okf, as[0]);  as[1] = fmaf(bfhi(ra.x), okf, as[1]);
    as[2] = fmaf(bflo(ra.y), okf, as[2]);  as[3] = fmaf(bfhi(ra.y), okf, as[3]);
    as[4] = fmaf(bflo(ra.z), okf, as[4]);  as[5] = fmaf(bfhi(ra.z), okf, as[5]);
    as[6] = fmaf(bflo(ra.w), okf, as[6]);  as[7] = fmaf(bfhi(ra.w), okf, as[7]);
    as[8] = fmaf(bflo(rb.x), okf, as[8]);  as[9] = fmaf(bfhi(rb.x), okf, as[9]);
    as[10] = fmaf(bflo(rb.y), okf, as[10]); as[11] = fmaf(bfhi(rb.y), okf, as[11]);
    as[12] = fmaf(bflo(rb.z), okf, as[12]); as[13] = fmaf(bfhi(rb.z), okf, as[13]);
    as[14] = fmaf(bflo(rb.w), okf, as[14]); as[15] = fmaf(bfhi(rb.w), okf, as[15]);
  }
#pragma unroll
  for (int off = 16; off >= 1; off >>= 1)
#pragma unroll
    for (int c = 0; c < 16; ++c) as[c] += __shfl_down(as[c], off, 64);
  // ---- node MLP on lanes l32<16 ----
  float aS[16], aR[16];
#pragma unroll
  for (int c = 0; c < 16; ++c) aS[c] = __shfl(as[c], half * 32, 64);
#pragma unroll
  for (int k = 0; k < 8; ++k) aR[k] = __shfl(ar[k], half * 32, 64);
#pragma unroll
  for (int k = 0; k < 8; ++k) aR[8 + k] = __shfl(ar[k], half * 32 + 1, 64);
  float nsv = nodesr[n];
  float pv = 0.f;
  if (l32 < 16) {
    int j = l32;
    float a1 = fmaf(nw1[j * 33], nsv, nb1_[j]);
#pragma unroll
    for (int k = 0; k < 16; ++k) a1 = fmaf(nw1[j * 33 + 1 + k], aS[k], a1);
#pragma unroll
    for (int k = 0; k < 16; ++k) a1 = fmaf(nw1[j * 33 + 17 + k], aR[k], a1);
    pv = nw2[j] * frelu(a1);
  }
#pragma unroll
  for (int off = 8; off >= 1; off >>= 1) pv += __shfl_down(pv, off, 64);
  if (l32 == 0) nodesw[n] = pv + nb2_[0];
}

// ---------------------------------------------------------------------------
// K7: edge MLP via MFMA (16x16x32 bf16). Per wave: 4 tiles of 16 edges.
// A = weights (row=lane&15, k=(lane>>4)*8+j — m156-verified k-mapping),
// B = edge features (col=lane&15, same k-mapping; 16 B contiguous load =
// k-ascending), C preloaded with bias. D: col=lane&15, row=(lane>>4)*4+reg
// (m89-verified). Layer-2 B built from layer-1 D via 8 shuffles. In-place
// safe: wave owns its 16-edge tile; loads precede stores in program order.
// ---------------------------------------------------------------------------
__global__ __launch_bounds__(256) void k_edgeM(
    unsigned short* __restrict__ e, const unsigned int* __restrict__ srecv,
    const unsigned int* __restrict__ ssend32, const float* __restrict__ nodes,
    const float* __restrict__ w1, const float* __restrict__ b1,
    const float* __restrict__ w2, const float* __restrict__ b2) {
  int wave = (blockIdx.x * blockDim.x + threadIdx.x) >> 6;
  int l = threadIdx.x & 63;
  int c = l & 15, kg = l >> 4;
  bf16x8 a1, a2;
#pragma unroll
  for (int j = 0; j < 8; ++j) {
    int k = kg * 8 + j;
    a1[j] = f2bs(k < 18 ? w1[c * 18 + k] : 0.f);   // A row = lane&15
    a2[j] = f2bs(k < 16 ? w2[c * 16 + k] : 0.f);
  }
  f32x4 c1, c2;
#pragma unroll
  for (int j = 0; j < 4; ++j) {
    c1[j] = b1[4 * kg + j];
    c2[j] = b2[4 * kg + j];
  }
  int T0 = wave * 64;
#pragma unroll
  for (int t = 0; t < 4; ++t) {
    int T = T0 + t * 16;
    int ec = T + c;
    bf16x8 bfrag = {};
    if (kg < 2) {
      uint4 raw = *(const uint4*)(e + (size_t)ec * HID + kg * 8);
      bfrag = *(bf16x8*)&raw;  // k = kg*8 + j, memory order
    } else if (kg == 2) {
      bfrag[0] = f2bs(nodes[ssend32[ec]]);  // k=16: ns
      bfrag[1] = f2bs(nodes[srecv[ec]]);    // k=17: nr
    }
    f32x4 d1 = __builtin_amdgcn_mfma_f32_16x16x32_bf16(a1, bfrag, c1, 0, 0, 0);
#pragma unroll
    for (int j = 0; j < 4; ++j) d1[j] = fmaxf(d1[j], 0.f);
    // B2: rows 0..15 = h (from d1), 16..31 = 0
    bf16x8 b2f = {};
    int src0 = ((2 * kg) * 16 + c) & 63;
    int src1 = ((2 * kg + 1) * 16 + c) & 63;
#pragma unroll
    for (int j = 0; j < 4; ++j) {
      float v = __shfl(d1[j], src0, 64);
      float w = __shfl(d1[j], src1, 64);
      if (kg < 2) {
        b2f[j] = f2bs(v);
        b2f[4 + j] = f2bs(w);
      }
    }
    f32x4 d2 = __builtin_amdgcn_mfma_f32_16x16x32_bf16(a2, b2f, c2, 0, 0, 0);
    unsigned int u0 = packbf(d2[0], d2[1]);
    unsigned int u1 = packbf(d2[2], d2[3]);
    *(uint2*)(e + (size_t)ec * HID + 4 * kg) = make_uint2(u0, u1);
  }
}

// ---------------------------------------------------------------------------
// K8: final via MFMA — edge MLP (2 MFMA) + decoder hidden (1 MFMA) + dot +
// cross-kg shuffle reduce. Writes delta only (scattered 4 B store).
// ---------------------------------------------------------------------------
__global__ __launch_bounds__(256) void k_final(
    const unsigned short* __restrict__ e, const unsigned int* __restrict__ srecv,
    const unsigned int* __restrict__ ssend32, const unsigned int* __restrict__ sorig,
    const float* __restrict__ nodes, const float* __restrict__ ew1,
    const float* __restrict__ eb1, const float* __restrict__ ew2,
    const float* __restrict__ eb2, const float* __restrict__ dw1,
    const float* __restrict__ db1, const float* __restrict__ dw2,
    const float* __restrict__ db2, const unsigned int* __restrict__ normbits,
    const float* __restrict__ alpha, float* __restrict__ out) {
  int wave = (blockIdx.x * blockDim.x + threadIdx.x) >> 6;
  int l = threadIdx.x & 63;
  int c = l & 15, kg = l >> 6 ? 0 : (l >> 4);  // kg = l>>4 (0..3)
  kg = l >> 4;
  bf16x8 a1, a2, a3;
#pragma unroll
  for (int j = 0; j < 8; ++j) {
    int k = kg * 8 + j;
    a1[j] = f2bs(k < 18 ? ew1[c * 18 + k] : 0.f);
    a2[j] = f2bs(k < 16 ? ew2[c * 16 + k] : 0.f);
    a3[j] = f2bs(k < 16 ? dw1[c * 16 + k] : 0.f);
  }
  f32x4 c1, c2, c3;
  float w2v[4];
#pragma unroll
  for (int j = 0; j < 4; ++j) {
    c1[j] = eb1[4 * kg + j];
    c2[j] = eb2[4 * kg + j];
    c3[j] = db1[4 * kg + j];
    w2v[j] = dw2[4 * kg + j];
  }
  float alphaN = alpha[0] * __uint_as_float(*normbits);
  float db2v = db2[0];
  int T0 = wave * 64;
#pragma unroll
  for (int t = 0; t < 4; ++t) {
    int T = T0 + t * 16;
    int ec = T + c;
    bf16x8 bfrag = {};
    if (kg < 2) {
      uint4 raw = *(const uint4*)(e + (size_t)ec * HID + kg * 8);
      bfrag = *(bf16x8*)&raw;
    } else if (kg == 2) {
      bfrag[0] = f2bs(nodes[ssend32[ec]]);
      bfrag[1] = f2bs(nodes[srecv[ec]]);
    }
    f32x4 d1 = __builtin_amdgcn_mfma_f32_16x16x32_bf16(a1, bfrag, c1, 0, 0, 0);
#pragma unroll
    for (int j = 0; j < 4; ++j) d1[j] = fmaxf(d1[j], 0.f);
    int src0 = ((2 * kg) * 16 + c) & 63;
    int src1 = ((2 * kg + 1) * 16 + c) & 63;
    bf16x8 b2f = {};
#pragma unroll
    for (int j = 0; j < 4; ++j) {
      float v = __shfl(d1[j], src0, 64);
      float w = __shfl(d1[j], src1, 64);
      if (kg < 2) {
        b2f[j] = f2bs(v);
        b2f[4 + j] = f2bs(w);
      }
    }
    f32x4 d2 = __builtin_amdgcn_mfma_f32_16x16x32_bf16(a2, b2f, c2, 0, 0, 0);
    // y (no relu) -> B3
    bf16x8 b3f = {};
#pragma unroll
    for (int j = 0; j < 4; ++j) {
      float v = __shfl(d2[j], src0, 64);
      float w = __shfl(d2[j], src1, 64);
      if (kg < 2) {
        b3f[j] = f2bs(v);
        b3f[4 + j] = f2bs(w);
      }
    }
    f32x4 d3 = __builtin_amdgcn_mfma_f32_16x16x32_bf16(a3, b3f, c3, 0, 0, 0);
    float p = 0.f;
#pragma unroll
    for (int j = 0; j < 4; ++j) p = fmaf(w2v[j], fmaxf(d3[j], 0.f), p);
    p += __shfl_down(p, 32, 64);
    p += __shfl_down(p, 16, 64);
    if (kg == 0) out[sorig[ec]] = alphaN * (p + db2v);
  }
}

// ---------------------------------------------------------------------------
// K9: residual add, fully coalesced: out[i] += edges_init[i]
// ---------------------------------------------------------------------------
__global__ __launch_bounds__(256) void k_resid(const float* __restrict__ edges,
                                               float* __restrict__ out) {
  int i = blockIdx.x * blockDim.x + threadIdx.x;
  out[i] += edges[i];
}

// ---------------------------------------------------------------------------
extern "C" void kernel_launch(void* const* d_in, const int* in_sizes, int n_in,
                              void* d_out, int out_size, void* d_ws,
                              size_t ws_size, hipStream_t stream) {
  const float* nodes0 = (const float*)d_in[0];
  const float* edges0 = (const float*)d_in[1];
  const int* senders = (const int*)d_in[2];
  const int* receivers = (const int*)d_in[3];
  const float* enc_w1 = (const float*)d_in[4];
  const float* enc_b1 = (const float*)d_in[5];
  const float* enc_w2 = (const float*)d_in[6];
  const float* enc_b2 = (const float*)d_in[7];
  const float* node_w1 = (const float*)d_in[8];
  const float* node_b1 = (const float*)d_in[9];
  const float* node_w2 = (const float*)d_in[10];
  const float* node_b2 = (const float*)d_in[11];
  const float* edge_w1 = (const float*)d_in[12];
  const float* edge_b1 = (const float*)d_in[13];
  const float* edge_w2 = (const float*)d_in[14];
  const float* edge_b2 = (const float*)d_in[15];
  const float* dec_w1 = (const float*)d_in[16];
  const float* dec_b1 = (const float*)d_in[17];
  const float* dec_w2 = (const float*)d_in[18];
  const float* dec_b2 = (const float*)d_in[19];
  const float* alpha = (const float*)d_in[20];

  // Workspace layout: ~162 MB (< proven 167.6 MB budget).
  char* ws = (char*)d_ws;
  unsigned short* e = (unsigned short*)ws;  // 3.2M x 32 B = 102.4 MB (sorted)
  char* p = ws + (size_t)N_EDGES * HID * 2;
  unsigned int* srecv = (unsigned int*)p;    p += (size_t)N_EDGES * 4;  // 12.8
  unsigned int* sorig = (unsigned int*)p;    p += (size_t)N_EDGES * 4;  // 12.8
  unsigned int* rlist = (unsigned int*)p;    p += (size_t)N_EDGES * 4;  // 12.8
  unsigned int* ssend32 = (unsigned int*)p;  p += (size_t)N_EDGES * 4;  // 12.8
  unsigned short* svalbf = (unsigned short*)p; p += (size_t)N_EDGES * 2;  // 6.4
  int* soff = (int*)p;                       p += (size_t)(N_NODES + 16) * 4;
  int* roff = (int*)p;                       p += (size_t)(N_NODES + 16) * 4;
  float* nbA = (float*)p;                    p += (size_t)N_NODES * 4;
  float* nbB = (float*)p;                    p += (size_t)N_NODES * 4;
  unsigned int* normbits = (unsigned int*)p; p += 64;
  int* gcnt = (int*)p;                       p += NB * 4;
  int* gcnt2 = (int*)p;                      p += NB * 4;
  // build staging aliases e (dead until k_encode):
  unsigned int* pM = (unsigned int*)ws;
  float* pV = (float*)(ws + (size_t)NB * SCAP * 4);
  unsigned int* pO = (unsigned int*)(ws + (size_t)NB * SCAP * 8);
  unsigned int* rpA = (unsigned int*)(ws + (size_t)NB * SCAP * 12);

  const int ngrid = 12500;   // 2 nodes/wave x 4 waves/block -> 100000 nodes
  const int egrid = N_EDGES / BLK;  // 12500
  const int mgrid = N_EDGES / 256;  // 12500: 4 waves x 64 edges per block

  hipMemsetAsync(normbits, 0, 64 + 2 * NB * 4, stream);  // norm + gcnt + gcnt2
  k_norm<<<512, BLK, 0, stream>>>(edges0, normbits);
  k_split<<<256, 1024, 0, stream>>>(senders, receivers, edges0, gcnt, pM, pV, pO);
  k_bsort1<<<NB, 1024, 0, stream>>>(pM, pV, pO, gcnt, srecv, sorig, svalbf,
                                    ssend32, soff);
  k_rsplit<<<256, 1024, 0, stream>>>(srecv, gcnt2, rpA);
  k_rsort<<<NB, 1024, 0, stream>>>(rpA, gcnt2, rlist, roff);
  k_encode<<<egrid, BLK, 0, stream>>>(svalbf, enc_w1, enc_b1, enc_w2, enc_b2,
                                      normbits, e);  // clobbers staging
  // round 1
  k_aggN<<<ngrid, BLK, 0, stream>>>(e, roff, rlist, soff, nodes0, node_w1,
                                    node_b1, node_w2, node_b2, nbA);
  k_edgeM<<<mgrid, BLK, 0, stream>>>(e, srecv, ssend32, nbA, edge_w1,
                                     edge_b1, edge_w2, edge_b2);
  // round 2
  k_aggN<<<ngrid, BLK, 0, stream>>>(e, roff, rlist, soff, nbA, node_w1,
                                    node_b1, node_w2, node_b2, nbB);
  k_edgeM<<<mgrid, BLK, 0, stream>>>(e, srecv, ssend32, nbB, edge_w1,
                                     edge_b1, edge_w2, edge_b2);
  // round 3
  k_aggN<<<ngrid, BLK, 0, stream>>>(e, roff, rlist, soff, nbB, node_w1,
                                    node_b1, node_w2, node_b2, nbA);
  // final: e3 = edgeMLP(e2, nbA) -> decoder -> delta; then residual add
  k_final<<<mgrid, BLK, 0, stream>>>(e, srecv, ssend32, sorig, nbA, edge_w1,
                                     edge_b1, edge_w2, edge_b2, dec_w1, dec_b1,
                                     dec_w2, dec_b2, normbits, alpha,
                                     (float*)d_out);
  k_resid<<<egrid, BLK, 0, stream>>>(edges0, (float*)d_out);
}

// Round 13
// 863.726 us; speedup vs baseline: 1.0488x; 1.0488x over previous
//
#include <hip/hip_runtime.h>
#include <hip/hip_bf16.h>

#define N_NODES 100000
#define N_EDGES 3200000
#define HID 16
#define NB 256       // buckets; bucket = NPB consecutive nodes
#define NPB 391      // 256*391 = 100096 >= 100000
#define SCAP 15360   // per-bucket staging cap (mean 12500, +25 sigma)
#define RCAP 15360
#define FDEPTH 32    // LDS FIFO depth in split kernels
#define LCAP1 8704   // bsort1 LDS chunk entries (12 B) -> ~102 KB
#define LCAP2 26624  // rsort LDS chunk entries (4 B) -> 104 KB (1 chunk/bucket)

static constexpr int BLK = 256;

__device__ __forceinline__ float frelu(float x) { return fmaxf(x, 0.f); }
__device__ __forceinline__ float bflo(unsigned int u) {
  return __uint_as_float(u << 16);
}
__device__ __forceinline__ float bfhi(unsigned int u) {
  return __uint_as_float(u & 0xFFFF0000u);
}
__device__ __forceinline__ unsigned int packbf(float lo, float hi) {
  __hip_bfloat16 hl = __float2bfloat16(lo), hh = __float2bfloat16(hi);
  return ((unsigned int)(*(unsigned short*)&hh) << 16) |
         (unsigned int)(*(unsigned short*)&hl);
}

union E16 {
  float4 f4[2];
  __hip_bfloat16 h[16];
};

// ---------------------------------------------------------------------------
// K0: norm = max |edges_init|
// ---------------------------------------------------------------------------
__global__ __launch_bounds__(256) void k_norm(const float* __restrict__ edges,
                                              unsigned int* __restrict__ normbits) {
  float m = 0.f;
  for (int i = blockIdx.x * blockDim.x + threadIdx.x; i < N_EDGES;
       i += gridDim.x * blockDim.x)
    m = fmaxf(m, fabsf(edges[i]));
#pragma unroll
  for (int off = 32; off > 0; off >>= 1)
    m = fmaxf(m, __shfl_down(m, off, 64));
  __shared__ float smax[BLK / 64];
  if ((threadIdx.x & 63) == 0) smax[threadIdx.x >> 6] = m;
  __syncthreads();
  if (threadIdx.x == 0) {
    float b = smax[0];
#pragma unroll
    for (int w = 1; w < BLK / 64; ++w) b = fmaxf(b, smax[w]);
    atomicMax(normbits, __float_as_uint(b));
  }
}

// ---------------------------------------------------------------------------
// K1: bucket edges by SENDER via LDS FIFOs (line-granular flushes).
// record: m = (sender_local<<22) | orig_edge(22b), v = edges_init, o = recv
// ---------------------------------------------------------------------------
__global__ __launch_bounds__(1024) void k_split(
    const int* __restrict__ senders, const int* __restrict__ receivers,
    const float* __restrict__ edges, int* __restrict__ gcnt,
    unsigned int* __restrict__ pM, float* __restrict__ pV,
    unsigned int* __restrict__ pO) {
  __shared__ __align__(16) unsigned int fM[NB][FDEPTH];
  __shared__ __align__(16) unsigned int fV[NB][FDEPTH];
  __shared__ __align__(16) unsigned int fO[NB][FDEPTH];
  __shared__ int fcnt[NB];
  const int t = threadIdx.x;
  if (t < NB) fcnt[t] = 0;
  __syncthreads();
  const int e0 = blockIdx.x * (N_EDGES / 256);
  const int e1 = e0 + (N_EDGES / 256);
  for (int base = e0; base < e1; base += 1024) {
    const int i = base + t;
    if (i < e1) {
      int s = senders[i];
      unsigned int b = (unsigned int)s / NPB;
      unsigned int m = (((unsigned int)s - b * NPB) << 22) | (unsigned int)i;
      unsigned int v = __float_as_uint(edges[i]);
      unsigned int o = (unsigned int)receivers[i];
      int pos = atomicAdd(&fcnt[b], 1);
      if (pos < FDEPTH) {
        fM[b][pos] = m; fV[b][pos] = v; fO[b][pos] = o;
      } else {  // rare overflow: direct append
        int gb = atomicAdd(&gcnt[b], 1);
        if (gb < SCAP) {
          pM[(size_t)b * SCAP + gb] = m;
          pV[(size_t)b * SCAP + gb] = __uint_as_float(v);
          pO[(size_t)b * SCAP + gb] = o;
        }
      }
    }
    __syncthreads();
    const bool last = (base + 1024 >= e1);
    if (t < NB) {
      int c = fcnt[t]; if (c > FDEPTH) c = FDEPTH;
      int nf = last ? c : (c & ~15);
      if (nf > 0) {
        int gb = atomicAdd(&gcnt[t], nf);
        size_t db = (size_t)t * SCAP + gb;
        if ((gb & 3) == 0 && gb + nf <= SCAP) {
          int k = 0;
          for (; k + 4 <= nf; k += 4) {
            *(uint4*)(pM + db + k) = *(const uint4*)(&fM[t][k]);
            *(uint4*)((unsigned int*)pV + db + k) = *(const uint4*)(&fV[t][k]);
            *(uint4*)(pO + db + k) = *(const uint4*)(&fO[t][k]);
          }
          for (; k < nf; ++k) {
            pM[db + k] = fM[t][k]; pV[db + k] = __uint_as_float(fV[t][k]);
            pO[db + k] = fO[t][k];
          }
        } else {
          for (int k = 0; k < nf; ++k)
            if (gb + k < SCAP) {
              pM[db + k] = fM[t][k]; pV[db + k] = __uint_as_float(fV[t][k]);
              pO[db + k] = fO[t][k];
            }
        }
        int res = c - nf;
        for (int k = 0; k < res; ++k) {
          fM[t][k] = fM[t][nf + k]; fV[t][k] = fV[t][nf + k];
          fO[t][k] = fO[t][nf + k];
        }
        fcnt[t] = res;
      } else fcnt[t] = c;
    }
    __syncthreads();
  }
}

// ---------------------------------------------------------------------------
// K2: per-bucket counting sort by sender_local -> EXACT global sender CSR.
// Writes srecv/sorig/svalbf/ssend32 (global sender id) + soff.
// ---------------------------------------------------------------------------
__global__ __launch_bounds__(1024) void k_bsort1(
    const unsigned int* __restrict__ pM, const float* __restrict__ pV,
    const unsigned int* __restrict__ pO, const int* __restrict__ gcnt,
    unsigned int* __restrict__ srecv, unsigned int* __restrict__ sorig,
    unsigned short* __restrict__ svalbf, unsigned int* __restrict__ ssend32,
    int* __restrict__ soff) {
  __shared__ unsigned int sM[LCAP1];
  __shared__ float sV[LCAP1];
  __shared__ unsigned int sO[LCAP1];
  __shared__ int hist[NPB], pref[NPB + 1], sc[NPB], cur[NPB];
  __shared__ int bb[NB];
  __shared__ int base_s;
  const int b = blockIdx.x, t = threadIdx.x, nt = blockDim.x;
  if (t < NB) { int c = gcnt[t]; bb[t] = c > SCAP ? SCAP : c; }
  for (int k = t; k < NPB; k += nt) hist[k] = 0;
  __syncthreads();
  if (t == 0) { int s = 0; for (int k = 0; k < b; ++k) s += bb[k]; base_s = s; }
  int nb = gcnt[b]; if (nb > SCAP) nb = SCAP;
  const unsigned int* PM = pM + (size_t)b * SCAP;
  const float* PV = pV + (size_t)b * SCAP;
  const unsigned int* PO = pO + (size_t)b * SCAP;
  for (int i = t; i < nb; i += nt) atomicAdd(&hist[PM[i] >> 22], 1);
  __syncthreads();
  if (t < NPB) sc[t] = hist[t];
  __syncthreads();
  for (int d = 1; d < NPB; d <<= 1) {
    int add = 0;
    if (t < NPB && t >= d) add = sc[t - d];
    __syncthreads();
    if (t < NPB && t >= d) sc[t] += add;
    __syncthreads();
  }
  if (t < NPB) pref[t] = sc[t] - hist[t];
  if (t == 0) pref[NPB] = sc[NPB - 1];
  __syncthreads();
  const int base = base_s;
  const int node0 = b * NPB;
  for (int k = t; k < NPB; k += nt) {
    int n = node0 + k;
    if (n < N_NODES) soff[n] = base + pref[k];
  }
  if (b == NB - 1 && t == 0) soff[N_NODES] = base + nb;
  __syncthreads();
  int klo = 0;
  while (klo < NPB) {
    int base0 = pref[klo];
    int khi = klo;
    while (khi < NPB && pref[khi + 1] - base0 <= LCAP1) ++khi;
    if (khi == klo) khi = klo + 1;  // safety
    for (int k = klo + t; k < khi; k += nt) cur[k] = pref[k];
    __syncthreads();
    for (int i = t; i < nb; i += nt) {
      unsigned int m = PM[i];
      int key = (int)(m >> 22);
      if (key >= klo && key < khi) {
        int p = atomicAdd(&cur[key], 1) - base0;
        if (p < LCAP1) { sM[p] = m; sV[p] = PV[i]; sO[p] = PO[i]; }
      }
    }
    __syncthreads();
    int csz = pref[khi] - base0;
    for (int i = t; i < csz; i += nt) {
      int g = base + base0 + i;
      unsigned int m = sM[i];
      srecv[g] = sO[i]; sorig[g] = m & 0x3FFFFFu;
      ssend32[g] = (unsigned int)(node0 + (int)(m >> 22));
      __hip_bfloat16 hb = __float2bfloat16(sV[i]);
      svalbf[g] = *(unsigned short*)&hb;
    }
    __syncthreads();
    klo = khi;
  }
}

// ---------------------------------------------------------------------------
// K3: bucket sorted edges by RECEIVER. a = (recv_local<<22) | sorted_idx
// ---------------------------------------------------------------------------
__global__ __launch_bounds__(1024) void k_rsplit(
    const unsigned int* __restrict__ srecv, int* __restrict__ gcnt2,
    unsigned int* __restrict__ rpA) {
  __shared__ __align__(16) unsigned int fA[NB][FDEPTH];
  __shared__ int fcnt[NB];
  const int t = threadIdx.x;
  if (t < NB) fcnt[t] = 0;
  __syncthreads();
  const int e0 = blockIdx.x * (N_EDGES / 256);
  const int e1 = e0 + (N_EDGES / 256);
  for (int base = e0; base < e1; base += 1024) {
    const int i = base + t;
    if (i < e1) {
      unsigned int r = srecv[i];
      unsigned int b = r / NPB;
      unsigned int a = ((r - b * NPB) << 22) | (unsigned int)i;
      int pos = atomicAdd(&fcnt[b], 1);
      if (pos < FDEPTH) {
        fA[b][pos] = a;
      } else {
        int gb = atomicAdd(&gcnt2[b], 1);
        if (gb < RCAP) rpA[(size_t)b * RCAP + gb] = a;
      }
    }
    __syncthreads();
    const bool last = (base + 1024 >= e1);
    if (t < NB) {
      int c = fcnt[t]; if (c > FDEPTH) c = FDEPTH;
      int nf = last ? c : (c & ~15);
      if (nf > 0) {
        int gb = atomicAdd(&gcnt2[t], nf);
        size_t db = (size_t)t * RCAP + gb;
        if ((gb & 3) == 0 && gb + nf <= RCAP) {
          int k = 0;
          for (; k + 4 <= nf; k += 4)
            *(uint4*)(rpA + db + k) = *(const uint4*)(&fA[t][k]);
          for (; k < nf; ++k) rpA[db + k] = fA[t][k];
        } else {
          for (int k = 0; k < nf; ++k)
            if (gb + k < RCAP) rpA[db + k] = fA[t][k];
        }
        int res = c - nf;
        for (int k = 0; k < res; ++k) fA[t][k] = fA[t][nf + k];
        fcnt[t] = res;
      } else fcnt[t] = c;
    }
    __syncthreads();
  }
}

// ---------------------------------------------------------------------------
// K4: per-bucket counting sort by recv_local -> receiver CSR (roff) + rlist.
// ---------------------------------------------------------------------------
__global__ __launch_bounds__(1024) void k_rsort(
    const unsigned int* __restrict__ rpA, const int* __restrict__ gcnt2,
    unsigned int* __restrict__ rlist, int* __restrict__ roff) {
  __shared__ unsigned int sA[LCAP2];
  __shared__ int hist[NPB], pref[NPB + 1], sc[NPB], cur[NPB];
  __shared__ int bb[NB];
  __shared__ int base_s;
  const int b = blockIdx.x, t = threadIdx.x, nt = blockDim.x;
  if (t < NB) { int c = gcnt2[t]; bb[t] = c > RCAP ? RCAP : c; }
  for (int k = t; k < NPB; k += nt) hist[k] = 0;
  __syncthreads();
  if (t == 0) { int s = 0; for (int k = 0; k < b; ++k) s += bb[k]; base_s = s; }
  int nb = gcnt2[b]; if (nb > RCAP) nb = RCAP;
  const unsigned int* PA = rpA + (size_t)b * RCAP;
  for (int i = t; i < nb; i += nt) atomicAdd(&hist[PA[i] >> 22], 1);
  __syncthreads();
  if (t < NPB) sc[t] = hist[t];
  __syncthreads();
  for (int d = 1; d < NPB; d <<= 1) {
    int add = 0;
    if (t < NPB && t >= d) add = sc[t - d];
    __syncthreads();
    if (t < NPB && t >= d) sc[t] += add;
    __syncthreads();
  }
  if (t < NPB) pref[t] = sc[t] - hist[t];
  if (t == 0) pref[NPB] = sc[NPB - 1];
  __syncthreads();
  const int base = base_s;
  const int node0 = b * NPB;
  for (int k = t; k < NPB; k += nt) {
    int n = node0 + k;
    if (n < N_NODES) roff[n] = base + pref[k];
  }
  if (b == NB - 1 && t == 0) roff[N_NODES] = base + nb;
  __syncthreads();
  int klo = 0;
  while (klo < NPB) {
    int base0 = pref[klo];
    int khi = klo;
    while (khi < NPB && pref[khi + 1] - base0 <= LCAP2) ++khi;
    if (khi == klo) khi = klo + 1;
    for (int k = klo + t; k < khi; k += nt) cur[k] = pref[k];
    __syncthreads();
    for (int i = t; i < nb; i += nt) {
      unsigned int a = PA[i];
      int key = (int)(a >> 22);
      if (key >= klo && key < khi) {
        int p = atomicAdd(&cur[key], 1) - base0;
        if (p < LCAP2) sA[p] = a;
      }
    }
    __syncthreads();
    int csz = pref[khi] - base0;
    for (int i = t; i < csz; i += nt)
      rlist[base + base0 + i] = sA[i] & 0x3FFFFFu;
    __syncthreads();
    klo = khi;
  }
}

// ---------------------------------------------------------------------------
// K5: edge encoder (1 -> HID -> HID) in sorted order, coalesced.
// ---------------------------------------------------------------------------
__global__ __launch_bounds__(256) void k_encode(
    const unsigned short* __restrict__ svalbf, const float* __restrict__ w1,
    const float* __restrict__ b1, const float* __restrict__ w2,
    const float* __restrict__ b2, const unsigned int* __restrict__ normbits,
    unsigned short* __restrict__ e) {
  int i = blockIdx.x * blockDim.x + threadIdx.x;
  float norm = __uint_as_float(*normbits);
  float x = bflo((unsigned int)svalbf[i]) / norm;
  float h[HID];
#pragma unroll
  for (int j = 0; j < HID; ++j) h[j] = frelu(fmaf(w1[j], x, b1[j]));
  E16 o;
#pragma unroll
  for (int j = 0; j < HID; ++j) {
    float acc = b2[j];
#pragma unroll
    for (int k = 0; k < HID; ++k) acc = fmaf(w2[j * HID + k], h[k], acc);
    o.h[j] = __float2bfloat16(acc);
  }
  float4* ep = (float4*)(e + (size_t)i * HID);
  ep[0] = o.f4[0];
  ep[1] = o.f4[1];
}

// ---------------------------------------------------------------------------
// K6: FUSED receiver-gather + sender-stream + node MLP, PHASES INTERLEAVED.
// Round-11 counters: phase A scatter-pipe-bound (~65us), phase B stream
// (~25us) ran AFTER it (BW 35%, VALU 32% — neither pipe full over the whole
// kernel). One merged loop issues an A-chunk (rlist + scattered 16 B) and a
// B-chunk (2x coalesced 16 B) per iteration so the stream traffic hides
// under scatter latency. Wave-uniform trip count (cross-half shuffle max);
// per-lane mask-as-FMA; OOB lanes re-load an L2-warm line (clamped idx).
// ---------------------------------------------------------------------------
__global__ __launch_bounds__(256) void k_aggN(
    const unsigned short* __restrict__ e, const int* __restrict__ roff,
    const unsigned int* __restrict__ rlist, const int* __restrict__ soff,
    const float* __restrict__ nodesr, const float* __restrict__ nw1,
    const float* __restrict__ nb1_, const float* __restrict__ nw2,
    const float* __restrict__ nb2_, float* __restrict__ nodesw) {
  int wave = (blockIdx.x * blockDim.x + threadIdx.x) >> 6;
  int lane = threadIdx.x & 63, half = lane >> 5, l32 = lane & 31;
  int n = wave * 2 + half;
  int sub = l32 & 1, j16 = l32 >> 1;
  int r0 = roff[n], rdeg = roff[n + 1] - r0;
  int s0 = soff[n], sdeg = soff[n + 1] - s0;
  int aSteps = (rdeg + 15) >> 4;   // per-half uniform
  int bSteps = (sdeg + 31) >> 5;
  int aO = __shfl_xor(aSteps, 32, 64);
  int bO = __shfl_xor(bSteps, 32, 64);
  int steps = max(max(aSteps, aO), max(bSteps, bO));  // wave-uniform
  float ar[8] = {0, 0, 0, 0, 0, 0, 0, 0};
  float as[16];
#pragma unroll
  for (int c = 0; c < 16; ++c) as[c] = 0.f;
  for (int s = 0; s < steps; ++s) {
    // ---- A-chunk: scattered receiver gather (2 lanes/entry, 16 B) ----
    int slotA = s * 16 + j16;
    bool okA = slotA < rdeg;
    int idxA = r0 + (okA ? slotA : 0);
    unsigned int si = rlist[idxA];
    uint4 rA = *(const uint4*)(e + (size_t)si * HID + sub * 8);
    // ---- B-chunk: coalesced sender stream (1 lane/edge, 32 B) ----
    int kB = s * 32 + l32;
    bool okB = kB < sdeg;
    int idxB = s0 + (okB ? kB : 0);
    uint4 ra = *(const uint4*)(e + (size_t)idxB * HID);
    uint4 rb = *(const uint4*)(e + (size_t)idxB * HID + 8);
    float fA = okA ? 1.f : 0.f;
    float fB = okB ? 1.f : 0.f;
    ar[0] = fmaf(bflo(rA.x), fA, ar[0]); ar[1] = fmaf(bfhi(rA.x), fA, ar[1]);
    ar[2] = fmaf(bflo(rA.y), fA, ar[2]); ar[3] = fmaf(bfhi(rA.y), fA, ar[3]);
    ar[4] = fmaf(bflo(rA.z), fA, ar[4]); ar[5] = fmaf(bfhi(rA.z), fA, ar[5]);
    ar[6] = fmaf(bflo(rA.w), fA, ar[6]); ar[7] = fmaf(bfhi(rA.w), fA, ar[7]);
    as[0] = fmaf(bflo(ra.x), fB, as[0]);  as[1] = fmaf(bfhi(ra.x), fB, as[1]);
    as[2] = fmaf(bflo(ra.y), fB, as[2]);  as[3] = fmaf(bfhi(ra.y), fB, as[3]);
    as[4] = fmaf(bflo(ra.z), fB, as[4]);  as[5] = fmaf(bfhi(ra.z), fB, as[5]);
    as[6] = fmaf(bflo(ra.w), fB, as[6]);  as[7] = fmaf(bfhi(ra.w), fB, as[7]);
    as[8] = fmaf(bflo(rb.x), fB, as[8]);  as[9] = fmaf(bfhi(rb.x), fB, as[9]);
    as[10] = fmaf(bflo(rb.y), fB, as[10]); as[11] = fmaf(bfhi(rb.y), fB, as[11]);
    as[12] = fmaf(bflo(rb.z), fB, as[12]); as[13] = fmaf(bfhi(rb.z), fB, as[13]);
    as[14] = fmaf(bflo(rb.w), fB, as[14]); as[15] = fmaf(bfhi(rb.w), fB, as[15]);
  }
#pragma unroll
  for (int off = 16; off >= 2; off >>= 1)
#pragma unroll
    for (int c = 0; c < 8; ++c) ar[c] += __shfl_down(ar[c], off, 64);
#pragma unroll
  for (int off = 16; off >= 1; off >>= 1)
#pragma unroll
    for (int c = 0; c < 16; ++c) as[c] += __shfl_down(as[c], off, 64);
  // ---- node MLP on lanes l32<16 ----
  float aS[16], aR[16];
#pragma unroll
  for (int c = 0; c < 16; ++c) aS[c] = __shfl(as[c], half * 32, 64);
#pragma unroll
  for (int k = 0; k < 8; ++k) aR[k] = __shfl(ar[k], half * 32, 64);
#pragma unroll
  for (int k = 0; k < 8; ++k) aR[8 + k] = __shfl(ar[k], half * 32 + 1, 64);
  float nsv = nodesr[n];
  float pv = 0.f;
  if (l32 < 16) {
    int j = l32;
    float a1 = fmaf(nw1[j * 33], nsv, nb1_[j]);
#pragma unroll
    for (int k = 0; k < 16; ++k) a1 = fmaf(nw1[j * 33 + 1 + k], aS[k], a1);
#pragma unroll
    for (int k = 0; k < 16; ++k) a1 = fmaf(nw1[j * 33 + 17 + k], aR[k], a1);
    pv = nw2[j] * frelu(a1);
  }
#pragma unroll
  for (int off = 8; off >= 1; off >>= 1) pv += __shfl_down(pv, off, 64);
  if (l32 == 0) nodesw[n] = pv + nb2_[0];
}

// ---------------------------------------------------------------------------
// K7: edge MLP, 2 EDGES PER THREAD (round-11 proven: 847 us build).
// Layer-2 chunked by 8 outputs with immediate 16 B stores. (256,4).
// ---------------------------------------------------------------------------
__global__ __launch_bounds__(256, 4) void k_edgeE(
    unsigned short* __restrict__ e, const unsigned int* __restrict__ srecv,
    const unsigned int* __restrict__ ssend32, const float* __restrict__ nodes,
    const float* __restrict__ w1, const float* __restrict__ b1,
    const float* __restrict__ w2, const float* __restrict__ b2) {
  int i0 = (blockIdx.x * blockDim.x + threadIdx.x) * 2;
  float ns[2], nr[2];
#pragma unroll
  for (int q = 0; q < 2; ++q) {
    ns[q] = nodes[ssend32[i0 + q]];
    nr[q] = nodes[srecv[i0 + q]];
  }
  unsigned int pk[2][8];
#pragma unroll
  for (int q = 0; q < 2; ++q) {
    const uint4* ep = (const uint4*)(e + (size_t)(i0 + q) * HID);
    uint4 ra = ep[0], rb = ep[1];
    pk[q][0] = ra.x; pk[q][1] = ra.y; pk[q][2] = ra.z; pk[q][3] = ra.w;
    pk[q][4] = rb.x; pk[q][5] = rb.y; pk[q][6] = rb.z; pk[q][7] = rb.w;
  }
  float h[2][16];
#pragma unroll
  for (int j = 0; j < 16; ++j) {
    float wA = w1[j * 18 + 16], wB = w1[j * 18 + 17], bb = b1[j];
#pragma unroll
    for (int q = 0; q < 2; ++q)
      h[q][j] = fmaf(wA, ns[q], fmaf(wB, nr[q], bb));
  }
#pragma unroll
  for (int kp = 0; kp < 8; ++kp) {
    float x0[2], x1[2];
#pragma unroll
    for (int q = 0; q < 2; ++q) {
      x0[q] = bflo(pk[q][kp]);
      x1[q] = bfhi(pk[q][kp]);
    }
#pragma unroll
    for (int j = 0; j < 16; ++j) {
      float wA = w1[j * 18 + 2 * kp], wB = w1[j * 18 + 2 * kp + 1];
#pragma unroll
      for (int q = 0; q < 2; ++q)
        h[q][j] = fmaf(wB, x1[q], fmaf(wA, x0[q], h[q][j]));
    }
  }
#pragma unroll
  for (int j = 0; j < 16; ++j)
#pragma unroll
    for (int q = 0; q < 2; ++q) h[q][j] = frelu(h[q][j]);
#pragma unroll
  for (int c0 = 0; c0 < 16; c0 += 8) {
    float y[2][8];
#pragma unroll
    for (int cc = 0; cc < 8; ++cc) {
      float bv = b2[c0 + cc];
#pragma unroll
      for (int q = 0; q < 2; ++q) y[q][cc] = bv;
    }
#pragma unroll
    for (int j = 0; j < 16; ++j) {
#pragma unroll
      for (int cc = 0; cc < 8; ++cc) {
        float wv = w2[(c0 + cc) * HID + j];
#pragma unroll
        for (int q = 0; q < 2; ++q) y[q][cc] = fmaf(wv, h[q][j], y[q][cc]);
      }
    }
#pragma unroll
    for (int q = 0; q < 2; ++q) {
      uint4 o = make_uint4(packbf(y[q][0], y[q][1]), packbf(y[q][2], y[q][3]),
                           packbf(y[q][4], y[q][5]), packbf(y[q][6], y[q][7]));
      *(uint4*)(e + (size_t)(i0 + q) * HID + c0) = o;
    }
  }
}

// ---------------------------------------------------------------------------
// K8: final — round-3 edge MLP + decoder, 2 EDGES PER THREAD (round-11
// proven). Writes delta only.
// ---------------------------------------------------------------------------
__global__ __launch_bounds__(256, 4) void k_final(
    const unsigned short* __restrict__ e, const unsigned int* __restrict__ srecv,
    const unsigned int* __restrict__ ssend32, const unsigned int* __restrict__ sorig,
    const float* __restrict__ nodes, const float* __restrict__ ew1,
    const float* __restrict__ eb1, const float* __restrict__ ew2,
    const float* __restrict__ eb2, const float* __restrict__ dw1,
    const float* __restrict__ db1, const float* __restrict__ dw2,
    const float* __restrict__ db2, const unsigned int* __restrict__ normbits,
    const float* __restrict__ alpha, float* __restrict__ out) {
  int i0 = (blockIdx.x * blockDim.x + threadIdx.x) * 2;
  float ns[2], nr[2];
#pragma unroll
  for (int q = 0; q < 2; ++q) {
    ns[q] = nodes[ssend32[i0 + q]];
    nr[q] = nodes[srecv[i0 + q]];
  }
  unsigned int pk[2][8];
#pragma unroll
  for (int q = 0; q < 2; ++q) {
    const uint4* ep = (const uint4*)(e + (size_t)(i0 + q) * HID);
    uint4 ra = ep[0], rb = ep[1];
    pk[q][0] = ra.x; pk[q][1] = ra.y; pk[q][2] = ra.z; pk[q][3] = ra.w;
    pk[q][4] = rb.x; pk[q][5] = rb.y; pk[q][6] = rb.z; pk[q][7] = rb.w;
  }
  float h[2][16];
#pragma unroll
  for (int j = 0; j < 16; ++j) {
    float wA = ew1[j * 18 + 16], wB = ew1[j * 18 + 17], bb = eb1[j];
#pragma unroll
    for (int q = 0; q < 2; ++q)
      h[q][j] = fmaf(wA, ns[q], fmaf(wB, nr[q], bb));
  }
#pragma unroll
  for (int kp = 0; kp < 8; ++kp) {
    float x0[2], x1[2];
#pragma unroll
    for (int q = 0; q < 2; ++q) {
      x0[q] = bflo(pk[q][kp]);
      x1[q] = bfhi(pk[q][kp]);
    }
#pragma unroll
    for (int j = 0; j < 16; ++j) {
      float wA = ew1[j * 18 + 2 * kp], wB = ew1[j * 18 + 2 * kp + 1];
#pragma unroll
      for (int q = 0; q < 2; ++q)
        h[q][j] = fmaf(wB, x1[q], fmaf(wA, x0[q], h[q][j]));
    }
  }
#pragma unroll
  for (int j = 0; j < 16; ++j)
#pragma unroll
    for (int q = 0; q < 2; ++q) h[q][j] = frelu(h[q][j]);
  float y[2][16];
#pragma unroll
  for (int c = 0; c < 16; ++c) {
    float bv = eb2[c];
#pragma unroll
    for (int q = 0; q < 2; ++q) y[q][c] = bv;
  }
#pragma unroll
  for (int j = 0; j < 16; ++j) {
#pragma unroll
    for (int c = 0; c < 16; ++c) {
      float wv = ew2[c * HID + j];
#pragma unroll
      for (int q = 0; q < 2; ++q) y[q][c] = fmaf(wv, h[q][j], y[q][c]);
    }
  }
  float d[2] = {db2[0], db2[0]};
#pragma unroll
  for (int j = 0; j < 16; ++j) {
    float a1[2] = {db1[j], db1[j]};
#pragma unroll
    for (int k = 0; k < 16; ++k) {
      float wv = dw1[j * HID + k];
#pragma unroll
      for (int q = 0; q < 2; ++q) a1[q] = fmaf(wv, y[q][k], a1[q]);
    }
    float wd = dw2[j];
#pragma unroll
    for (int q = 0; q < 2; ++q) d[q] = fmaf(wd, frelu(a1[q]), d[q]);
  }
  float alphaN = alpha[0] * __uint_as_float(*normbits);
#pragma unroll
  for (int q = 0; q < 2; ++q) out[sorig[i0 + q]] = alphaN * d[q];
}

// ---------------------------------------------------------------------------
// K9: residual add, fully coalesced: out[i] += edges_init[i]
// ---------------------------------------------------------------------------
__global__ __launch_bounds__(256) void k_resid(const float* __restrict__ edges,
                                               float* __restrict__ out) {
  int i = blockIdx.x * blockDim.x + threadIdx.x;
  out[i] += edges[i];
}

// ---------------------------------------------------------------------------
extern "C" void kernel_launch(void* const* d_in, const int* in_sizes, int n_in,
                              void* d_out, int out_size, void* d_ws,
                              size_t ws_size, hipStream_t stream) {
  const float* nodes0 = (const float*)d_in[0];
  const float* edges0 = (const float*)d_in[1];
  const int* senders = (const int*)d_in[2];
  const int* receivers = (const int*)d_in[3];
  const float* enc_w1 = (const float*)d_in[4];
  const float* enc_b1 = (const float*)d_in[5];
  const float* enc_w2 = (const float*)d_in[6];
  const float* enc_b2 = (const float*)d_in[7];
  const float* node_w1 = (const float*)d_in[8];
  const float* node_b1 = (const float*)d_in[9];
  const float* node_w2 = (const float*)d_in[10];
  const float* node_b2 = (const float*)d_in[11];
  const float* edge_w1 = (const float*)d_in[12];
  const float* edge_b1 = (const float*)d_in[13];
  const float* edge_w2 = (const float*)d_in[14];
  const float* edge_b2 = (const float*)d_in[15];
  const float* dec_w1 = (const float*)d_in[16];
  const float* dec_b1 = (const float*)d_in[17];
  const float* dec_w2 = (const float*)d_in[18];
  const float* dec_b2 = (const float*)d_in[19];
  const float* alpha = (const float*)d_in[20];

  // Workspace layout: ~162 MB (< proven 167.6 MB budget).
  char* ws = (char*)d_ws;
  unsigned short* e = (unsigned short*)ws;  // 3.2M x 32 B = 102.4 MB (sorted)
  char* p = ws + (size_t)N_EDGES * HID * 2;
  unsigned int* srecv = (unsigned int*)p;    p += (size_t)N_EDGES * 4;  // 12.8
  unsigned int* sorig = (unsigned int*)p;    p += (size_t)N_EDGES * 4;  // 12.8
  unsigned int* rlist = (unsigned int*)p;    p += (size_t)N_EDGES * 4;  // 12.8
  unsigned int* ssend32 = (unsigned int*)p;  p += (size_t)N_EDGES * 4;  // 12.8
  unsigned short* svalbf = (unsigned short*)p; p += (size_t)N_EDGES * 2;  // 6.4
  int* soff = (int*)p;                       p += (size_t)(N_NODES + 16) * 4;
  int* roff = (int*)p;                       p += (size_t)(N_NODES + 16) * 4;
  float* nbA = (float*)p;                    p += (size_t)N_NODES * 4;
  float* nbB = (float*)p;                    p += (size_t)N_NODES * 4;
  unsigned int* normbits = (unsigned int*)p; p += 64;
  int* gcnt = (int*)p;                       p += NB * 4;
  int* gcnt2 = (int*)p;                      p += NB * 4;
  // build staging aliases e (dead until k_encode):
  unsigned int* pM = (unsigned int*)ws;
  float* pV = (float*)(ws + (size_t)NB * SCAP * 4);
  unsigned int* pO = (unsigned int*)(ws + (size_t)NB * SCAP * 8);
  unsigned int* rpA = (unsigned int*)(ws + (size_t)NB * SCAP * 12);

  const int ngrid = 12500;   // 2 nodes/wave x 4 waves/block -> 100000 nodes
  const int egrid = N_EDGES / BLK;        // 12500
  const int egrid2 = N_EDGES / (BLK * 2); // 6250 (2 edges/thread)

  hipMemsetAsync(normbits, 0, 64 + 2 * NB * 4, stream);  // norm + gcnt + gcnt2
  k_norm<<<512, BLK, 0, stream>>>(edges0, normbits);
  k_split<<<256, 1024, 0, stream>>>(senders, receivers, edges0, gcnt, pM, pV, pO);
  k_bsort1<<<NB, 1024, 0, stream>>>(pM, pV, pO, gcnt, srecv, sorig, svalbf,
                                    ssend32, soff);
  k_rsplit<<<256, 1024, 0, stream>>>(srecv, gcnt2, rpA);
  k_rsort<<<NB, 1024, 0, stream>>>(rpA, gcnt2, rlist, roff);
  k_encode<<<egrid, BLK, 0, stream>>>(svalbf, enc_w1, enc_b1, enc_w2, enc_b2,
                                      normbits, e);  // clobbers staging
  // round 1
  k_aggN<<<ngrid, BLK, 0, stream>>>(e, roff, rlist, soff, nodes0, node_w1,
                                    node_b1, node_w2, node_b2, nbA);
  k_edgeE<<<egrid2, BLK, 0, stream>>>(e, srecv, ssend32, nbA, edge_w1,
                                      edge_b1, edge_w2, edge_b2);
  // round 2
  k_aggN<<<ngrid, BLK, 0, stream>>>(e, roff, rlist, soff, nbA, node_w1,
                                    node_b1, node_w2, node_b2, nbB);
  k_edgeE<<<egrid2, BLK, 0, stream>>>(e, srecv, ssend32, nbB, edge_w1,
                                      edge_b1, edge_w2, edge_b2);
  // round 3
  k_aggN<<<ngrid, BLK, 0, stream>>>(e, roff, rlist, soff, nbB, node_w1,
                                    node_b1, node_w2, node_b2, nbA);
  // final: e3 = edgeMLP(e2, nbA) -> decoder -> delta; then residual add
  k_final<<<egrid2, BLK, 0, stream>>>(e, srecv, ssend32, sorig, nbA, edge_w1,
                                      edge_b1, edge_w2, edge_b2, dec_w1,
                                      dec_b1, dec_w2, dec_b2, normbits, alpha,
                                      (float*)d_out);
  k_resid<<<egrid, BLK, 0, stream>>>(edges0, (float*)d_out);
}

// Round 14
// 847.439 us; speedup vs baseline: 1.0689x; 1.0192x over previous
//
#include <hip/hip_runtime.h>
#include <hip/hip_bf16.h>

#define N_NODES 100000
#define N_EDGES 3200000
#define HID 16
#define NB 256       // buckets; bucket = NPB consecutive nodes
#define NPB 391      // 256*391 = 100096 >= 100000
#define SCAP 15360   // per-bucket staging cap (mean 12500, +25 sigma)
#define RCAP 15360
#define FDEPTH 32    // LDS FIFO depth in split kernels
#define LCAP1 8704   // bsort1 LDS chunk entries (12 B) -> ~102 KB
#define LCAP2 26624  // rsort LDS chunk entries (4 B) -> 104 KB (1 chunk/bucket)

static constexpr int BLK = 256;

__device__ __forceinline__ float frelu(float x) { return fmaxf(x, 0.f); }
__device__ __forceinline__ float bflo(unsigned int u) {
  return __uint_as_float(u << 16);
}
__device__ __forceinline__ float bfhi(unsigned int u) {
  return __uint_as_float(u & 0xFFFF0000u);
}
__device__ __forceinline__ unsigned int packbf(float lo, float hi) {
  __hip_bfloat16 hl = __float2bfloat16(lo), hh = __float2bfloat16(hi);
  return ((unsigned int)(*(unsigned short*)&hh) << 16) |
         (unsigned int)(*(unsigned short*)&hl);
}

union E16 {
  float4 f4[2];
  __hip_bfloat16 h[16];
};

// ---------------------------------------------------------------------------
// K0: norm = max |edges_init|
// ---------------------------------------------------------------------------
__global__ __launch_bounds__(256) void k_norm(const float* __restrict__ edges,
                                              unsigned int* __restrict__ normbits) {
  float m = 0.f;
  for (int i = blockIdx.x * blockDim.x + threadIdx.x; i < N_EDGES;
       i += gridDim.x * blockDim.x)
    m = fmaxf(m, fabsf(edges[i]));
#pragma unroll
  for (int off = 32; off > 0; off >>= 1)
    m = fmaxf(m, __shfl_down(m, off, 64));
  __shared__ float smax[BLK / 64];
  if ((threadIdx.x & 63) == 0) smax[threadIdx.x >> 6] = m;
  __syncthreads();
  if (threadIdx.x == 0) {
    float b = smax[0];
#pragma unroll
    for (int w = 1; w < BLK / 64; ++w) b = fmaxf(b, smax[w]);
    atomicMax(normbits, __float_as_uint(b));
  }
}

// ---------------------------------------------------------------------------
// K1: bucket edges by SENDER via LDS FIFOs (line-granular flushes).
// record: m = (sender_local<<22) | orig_edge(22b), v = edges_init, o = recv
// ---------------------------------------------------------------------------
__global__ __launch_bounds__(1024) void k_split(
    const int* __restrict__ senders, const int* __restrict__ receivers,
    const float* __restrict__ edges, int* __restrict__ gcnt,
    unsigned int* __restrict__ pM, float* __restrict__ pV,
    unsigned int* __restrict__ pO) {
  __shared__ __align__(16) unsigned int fM[NB][FDEPTH];
  __shared__ __align__(16) unsigned int fV[NB][FDEPTH];
  __shared__ __align__(16) unsigned int fO[NB][FDEPTH];
  __shared__ int fcnt[NB];
  const int t = threadIdx.x;
  if (t < NB) fcnt[t] = 0;
  __syncthreads();
  const int e0 = blockIdx.x * (N_EDGES / 256);
  const int e1 = e0 + (N_EDGES / 256);
  for (int base = e0; base < e1; base += 1024) {
    const int i = base + t;
    if (i < e1) {
      int s = senders[i];
      unsigned int b = (unsigned int)s / NPB;
      unsigned int m = (((unsigned int)s - b * NPB) << 22) | (unsigned int)i;
      unsigned int v = __float_as_uint(edges[i]);
      unsigned int o = (unsigned int)receivers[i];
      int pos = atomicAdd(&fcnt[b], 1);
      if (pos < FDEPTH) {
        fM[b][pos] = m; fV[b][pos] = v; fO[b][pos] = o;
      } else {  // rare overflow: direct append
        int gb = atomicAdd(&gcnt[b], 1);
        if (gb < SCAP) {
          pM[(size_t)b * SCAP + gb] = m;
          pV[(size_t)b * SCAP + gb] = __uint_as_float(v);
          pO[(size_t)b * SCAP + gb] = o;
        }
      }
    }
    __syncthreads();
    const bool last = (base + 1024 >= e1);
    if (t < NB) {
      int c = fcnt[t]; if (c > FDEPTH) c = FDEPTH;
      int nf = last ? c : (c & ~15);
      if (nf > 0) {
        int gb = atomicAdd(&gcnt[t], nf);
        size_t db = (size_t)t * SCAP + gb;
        if ((gb & 3) == 0 && gb + nf <= SCAP) {
          int k = 0;
          for (; k + 4 <= nf; k += 4) {
            *(uint4*)(pM + db + k) = *(const uint4*)(&fM[t][k]);
            *(uint4*)((unsigned int*)pV + db + k) = *(const uint4*)(&fV[t][k]);
            *(uint4*)(pO + db + k) = *(const uint4*)(&fO[t][k]);
          }
          for (; k < nf; ++k) {
            pM[db + k] = fM[t][k]; pV[db + k] = __uint_as_float(fV[t][k]);
            pO[db + k] = fO[t][k];
          }
        } else {
          for (int k = 0; k < nf; ++k)
            if (gb + k < SCAP) {
              pM[db + k] = fM[t][k]; pV[db + k] = __uint_as_float(fV[t][k]);
              pO[db + k] = fO[t][k];
            }
        }
        int res = c - nf;
        for (int k = 0; k < res; ++k) {
          fM[t][k] = fM[t][nf + k]; fV[t][k] = fV[t][nf + k];
          fO[t][k] = fO[t][nf + k];
        }
        fcnt[t] = res;
      } else fcnt[t] = c;
    }
    __syncthreads();
  }
}

// ---------------------------------------------------------------------------
// K2: per-bucket counting sort by sender_local -> EXACT global sender CSR.
// Writes srecv/sorig/svalbf/ssend32 (global sender id) + soff.
// ---------------------------------------------------------------------------
__global__ __launch_bounds__(1024) void k_bsort1(
    const unsigned int* __restrict__ pM, const float* __restrict__ pV,
    const unsigned int* __restrict__ pO, const int* __restrict__ gcnt,
    unsigned int* __restrict__ srecv, unsigned int* __restrict__ sorig,
    unsigned short* __restrict__ svalbf, unsigned int* __restrict__ ssend32,
    int* __restrict__ soff) {
  __shared__ unsigned int sM[LCAP1];
  __shared__ float sV[LCAP1];
  __shared__ unsigned int sO[LCAP1];
  __shared__ int hist[NPB], pref[NPB + 1], sc[NPB], cur[NPB];
  __shared__ int bb[NB];
  __shared__ int base_s;
  const int b = blockIdx.x, t = threadIdx.x, nt = blockDim.x;
  if (t < NB) { int c = gcnt[t]; bb[t] = c > SCAP ? SCAP : c; }
  for (int k = t; k < NPB; k += nt) hist[k] = 0;
  __syncthreads();
  if (t == 0) { int s = 0; for (int k = 0; k < b; ++k) s += bb[k]; base_s = s; }
  int nb = gcnt[b]; if (nb > SCAP) nb = SCAP;
  const unsigned int* PM = pM + (size_t)b * SCAP;
  const float* PV = pV + (size_t)b * SCAP;
  const unsigned int* PO = pO + (size_t)b * SCAP;
  for (int i = t; i < nb; i += nt) atomicAdd(&hist[PM[i] >> 22], 1);
  __syncthreads();
  if (t < NPB) sc[t] = hist[t];
  __syncthreads();
  for (int d = 1; d < NPB; d <<= 1) {
    int add = 0;
    if (t < NPB && t >= d) add = sc[t - d];
    __syncthreads();
    if (t < NPB && t >= d) sc[t] += add;
    __syncthreads();
  }
  if (t < NPB) pref[t] = sc[t] - hist[t];
  if (t == 0) pref[NPB] = sc[NPB - 1];
  __syncthreads();
  const int base = base_s;
  const int node0 = b * NPB;
  for (int k = t; k < NPB; k += nt) {
    int n = node0 + k;
    if (n < N_NODES) soff[n] = base + pref[k];
  }
  if (b == NB - 1 && t == 0) soff[N_NODES] = base + nb;
  __syncthreads();
  int klo = 0;
  while (klo < NPB) {
    int base0 = pref[klo];
    int khi = klo;
    while (khi < NPB && pref[khi + 1] - base0 <= LCAP1) ++khi;
    if (khi == klo) khi = klo + 1;  // safety
    for (int k = klo + t; k < khi; k += nt) cur[k] = pref[k];
    __syncthreads();
    for (int i = t; i < nb; i += nt) {
      unsigned int m = PM[i];
      int key = (int)(m >> 22);
      if (key >= klo && key < khi) {
        int p = atomicAdd(&cur[key], 1) - base0;
        if (p < LCAP1) { sM[p] = m; sV[p] = PV[i]; sO[p] = PO[i]; }
      }
    }
    __syncthreads();
    int csz = pref[khi] - base0;
    for (int i = t; i < csz; i += nt) {
      int g = base + base0 + i;
      unsigned int m = sM[i];
      srecv[g] = sO[i]; sorig[g] = m & 0x3FFFFFu;
      ssend32[g] = (unsigned int)(node0 + (int)(m >> 22));
      __hip_bfloat16 hb = __float2bfloat16(sV[i]);
      svalbf[g] = *(unsigned short*)&hb;
    }
    __syncthreads();
    klo = khi;
  }
}

// ---------------------------------------------------------------------------
// K3: bucket sorted edges by RECEIVER. a = (recv_local<<22) | sorted_idx
// ---------------------------------------------------------------------------
__global__ __launch_bounds__(1024) void k_rsplit(
    const unsigned int* __restrict__ srecv, int* __restrict__ gcnt2,
    unsigned int* __restrict__ rpA) {
  __shared__ __align__(16) unsigned int fA[NB][FDEPTH];
  __shared__ int fcnt[NB];
  const int t = threadIdx.x;
  if (t < NB) fcnt[t] = 0;
  __syncthreads();
  const int e0 = blockIdx.x * (N_EDGES / 256);
  const int e1 = e0 + (N_EDGES / 256);
  for (int base = e0; base < e1; base += 1024) {
    const int i = base + t;
    if (i < e1) {
      unsigned int r = srecv[i];
      unsigned int b = r / NPB;
      unsigned int a = ((r - b * NPB) << 22) | (unsigned int)i;
      int pos = atomicAdd(&fcnt[b], 1);
      if (pos < FDEPTH) {
        fA[b][pos] = a;
      } else {
        int gb = atomicAdd(&gcnt2[b], 1);
        if (gb < RCAP) rpA[(size_t)b * RCAP + gb] = a;
      }
    }
    __syncthreads();
    const bool last = (base + 1024 >= e1);
    if (t < NB) {
      int c = fcnt[t]; if (c > FDEPTH) c = FDEPTH;
      int nf = last ? c : (c & ~15);
      if (nf > 0) {
        int gb = atomicAdd(&gcnt2[t], nf);
        size_t db = (size_t)t * RCAP + gb;
        if ((gb & 3) == 0 && gb + nf <= RCAP) {
          int k = 0;
          for (; k + 4 <= nf; k += 4)
            *(uint4*)(rpA + db + k) = *(const uint4*)(&fA[t][k]);
          for (; k < nf; ++k) rpA[db + k] = fA[t][k];
        } else {
          for (int k = 0; k < nf; ++k)
            if (gb + k < RCAP) rpA[db + k] = fA[t][k];
        }
        int res = c - nf;
        for (int k = 0; k < res; ++k) fA[t][k] = fA[t][nf + k];
        fcnt[t] = res;
      } else fcnt[t] = c;
    }
    __syncthreads();
  }
}

// ---------------------------------------------------------------------------
// K4: per-bucket counting sort by recv_local -> receiver CSR (roff) + rlist.
// ---------------------------------------------------------------------------
__global__ __launch_bounds__(1024) void k_rsort(
    const unsigned int* __restrict__ rpA, const int* __restrict__ gcnt2,
    unsigned int* __restrict__ rlist, int* __restrict__ roff) {
  __shared__ unsigned int sA[LCAP2];
  __shared__ int hist[NPB], pref[NPB + 1], sc[NPB], cur[NPB];
  __shared__ int bb[NB];
  __shared__ int base_s;
  const int b = blockIdx.x, t = threadIdx.x, nt = blockDim.x;
  if (t < NB) { int c = gcnt2[t]; bb[t] = c > RCAP ? RCAP : c; }
  for (int k = t; k < NPB; k += nt) hist[k] = 0;
  __syncthreads();
  if (t == 0) { int s = 0; for (int k = 0; k < b; ++k) s += bb[k]; base_s = s; }
  int nb = gcnt2[b]; if (nb > RCAP) nb = RCAP;
  const unsigned int* PA = rpA + (size_t)b * RCAP;
  for (int i = t; i < nb; i += nt) atomicAdd(&hist[PA[i] >> 22], 1);
  __syncthreads();
  if (t < NPB) sc[t] = hist[t];
  __syncthreads();
  for (int d = 1; d < NPB; d <<= 1) {
    int add = 0;
    if (t < NPB && t >= d) add = sc[t - d];
    __syncthreads();
    if (t < NPB && t >= d) sc[t] += add;
    __syncthreads();
  }
  if (t < NPB) pref[t] = sc[t] - hist[t];
  if (t == 0) pref[NPB] = sc[NPB - 1];
  __syncthreads();
  const int base = base_s;
  const int node0 = b * NPB;
  for (int k = t; k < NPB; k += nt) {
    int n = node0 + k;
    if (n < N_NODES) roff[n] = base + pref[k];
  }
  if (b == NB - 1 && t == 0) roff[N_NODES] = base + nb;
  __syncthreads();
  int klo = 0;
  while (klo < NPB) {
    int base0 = pref[klo];
    int khi = klo;
    while (khi < NPB && pref[khi + 1] - base0 <= LCAP2) ++khi;
    if (khi == klo) khi = klo + 1;
    for (int k = klo + t; k < khi; k += nt) cur[k] = pref[k];
    __syncthreads();
    for (int i = t; i < nb; i += nt) {
      unsigned int a = PA[i];
      int key = (int)(a >> 22);
      if (key >= klo && key < khi) {
        int p = atomicAdd(&cur[key], 1) - base0;
        if (p < LCAP2) sA[p] = a;
      }
    }
    __syncthreads();
    int csz = pref[khi] - base0;
    for (int i = t; i < csz; i += nt)
      rlist[base + base0 + i] = sA[i] & 0x3FFFFFu;
    __syncthreads();
    klo = khi;
  }
}

// ---------------------------------------------------------------------------
// K5: edge encoder (1 -> HID -> HID) in sorted order, coalesced.
// ---------------------------------------------------------------------------
__global__ __launch_bounds__(256) void k_encode(
    const unsigned short* __restrict__ svalbf, const float* __restrict__ w1,
    const float* __restrict__ b1, const float* __restrict__ w2,
    const float* __restrict__ b2, const unsigned int* __restrict__ normbits,
    unsigned short* __restrict__ e) {
  int i = blockIdx.x * blockDim.x + threadIdx.x;
  float norm = __uint_as_float(*normbits);
  float x = bflo((unsigned int)svalbf[i]) / norm;
  float h[HID];
#pragma unroll
  for (int j = 0; j < HID; ++j) h[j] = frelu(fmaf(w1[j], x, b1[j]));
  E16 o;
#pragma unroll
  for (int j = 0; j < HID; ++j) {
    float acc = b2[j];
#pragma unroll
    for (int k = 0; k < HID; ++k) acc = fmaf(w2[j * HID + k], h[k], acc);
    o.h[j] = __float2bfloat16(acc);
  }
  float4* ep = (float4*)(e + (size_t)i * HID);
  ep[0] = o.f4[0];
  ep[1] = o.f4[1];
}

// ---------------------------------------------------------------------------
// K6: FUSED receiver-gather + sender-stream + node MLP. Phase A unrolled x2.
// Round-13 A/B closed the investigation: sequential phases (this form) beat
// the merged interleave (92.6 vs 96.6 us) — wave-level TLP already overlaps
// the scatter and stream pipes; ~93 us is the measured floor.
// ---------------------------------------------------------------------------
__global__ __launch_bounds__(256) void k_aggN(
    const unsigned short* __restrict__ e, const int* __restrict__ roff,
    const unsigned int* __restrict__ rlist, const int* __restrict__ soff,
    const float* __restrict__ nodesr, const float* __restrict__ nw1,
    const float* __restrict__ nb1_, const float* __restrict__ nw2,
    const float* __restrict__ nb2_, float* __restrict__ nodesw) {
  int wave = (blockIdx.x * blockDim.x + threadIdx.x) >> 6;
  int lane = threadIdx.x & 63, half = lane >> 5, l32 = lane & 31;
  int n = wave * 2 + half;
  // ---- phase A: receiver-side scattered gather (x2 unrolled) ----
  int sub = l32 & 1, j16 = l32 >> 1;
  int r0 = roff[n], rdeg = roff[n + 1] - r0;
  float ar[8] = {0, 0, 0, 0, 0, 0, 0, 0};
  int q0 = 0;
  int full2 = rdeg & ~31;
  for (; q0 < full2; q0 += 32) {
    int idx0 = r0 + q0 + j16;
    unsigned int si0 = rlist[idx0];
    unsigned int si1 = rlist[idx0 + 16];
    uint4 ra = *(const uint4*)(e + (size_t)si0 * HID + sub * 8);
    uint4 rb = *(const uint4*)(e + (size_t)si1 * HID + sub * 8);
    ar[0] += bflo(ra.x); ar[1] += bfhi(ra.x);
    ar[2] += bflo(ra.y); ar[3] += bfhi(ra.y);
    ar[4] += bflo(ra.z); ar[5] += bfhi(ra.z);
    ar[6] += bflo(ra.w); ar[7] += bfhi(ra.w);
    ar[0] += bflo(rb.x); ar[1] += bfhi(rb.x);
    ar[2] += bflo(rb.y); ar[3] += bfhi(rb.y);
    ar[4] += bflo(rb.z); ar[5] += bfhi(rb.z);
    ar[6] += bflo(rb.w); ar[7] += bfhi(rb.w);
  }
  if (q0 + 16 <= rdeg) {
    int idx = r0 + q0 + j16;
    unsigned int si = rlist[idx];
    uint4 raw = *(const uint4*)(e + (size_t)si * HID + sub * 8);
    ar[0] += bflo(raw.x); ar[1] += bfhi(raw.x);
    ar[2] += bflo(raw.y); ar[3] += bfhi(raw.y);
    ar[4] += bflo(raw.z); ar[5] += bfhi(raw.z);
    ar[6] += bflo(raw.w); ar[7] += bfhi(raw.w);
    q0 += 16;
  }
  if (q0 < rdeg) {
    int slot = q0 + j16;
    bool ok = slot < rdeg;
    int idx = r0 + (ok ? slot : 0);
    unsigned int si = rlist[idx];
    uint4 raw = *(const uint4*)(e + (size_t)si * HID + sub * 8);
    float okf = ok ? 1.f : 0.f;
    ar[0] = fmaf(bflo(raw.x), okf, ar[0]); ar[1] = fmaf(bfhi(raw.x), okf, ar[1]);
    ar[2] = fmaf(bflo(raw.y), okf, ar[2]); ar[3] = fmaf(bfhi(raw.y), okf, ar[3]);
    ar[4] = fmaf(bflo(raw.z), okf, ar[4]); ar[5] = fmaf(bfhi(raw.z), okf, ar[5]);
    ar[6] = fmaf(bflo(raw.w), okf, ar[6]); ar[7] = fmaf(bfhi(raw.w), okf, ar[7]);
  }
#pragma unroll
  for (int off = 16; off >= 2; off >>= 1)
#pragma unroll
    for (int c = 0; c < 8; ++c) ar[c] += __shfl_down(ar[c], off, 64);
  // ---- phase B: sender-side coalesced stream ----
  int s0 = soff[n], sdeg = soff[n + 1] - s0;
  float as[16];
#pragma unroll
  for (int c = 0; c < 16; ++c) as[c] = 0.f;
  int fullB = sdeg & ~31;
  int c0 = 0;
  for (; c0 < fullB; c0 += 32) {
    int idx = s0 + c0 + l32;
    uint4 ra = *(const uint4*)(e + (size_t)idx * HID);
    uint4 rb = *(const uint4*)(e + (size_t)idx * HID + 8);
    as[0] += bflo(ra.x);  as[1] += bfhi(ra.x);
    as[2] += bflo(ra.y);  as[3] += bfhi(ra.y);
    as[4] += bflo(ra.z);  as[5] += bfhi(ra.z);
    as[6] += bflo(ra.w);  as[7] += bfhi(ra.w);
    as[8] += bflo(rb.x);  as[9] += bfhi(rb.x);
    as[10] += bflo(rb.y); as[11] += bfhi(rb.y);
    as[12] += bflo(rb.z); as[13] += bfhi(rb.z);
    as[14] += bflo(rb.w); as[15] += bfhi(rb.w);
  }
  if (c0 < sdeg) {
    int k = c0 + l32;
    bool ok = k < sdeg;
    int idx = s0 + (ok ? k : 0);
    uint4 ra = *(const uint4*)(e + (size_t)idx * HID);
    uint4 rb = *(const uint4*)(e + (size_t)idx * HID + 8);
    float okf = ok ? 1.f : 0.f;
    as[0] = fmaf(bflo(ra.x), okf, as[0]);  as[1] = fmaf(bfhi(ra.x), okf, as[1]);
    as[2] = fmaf(bflo(ra.y), okf, as[2]);  as[3] = fmaf(bfhi(ra.y), okf, as[3]);
    as[4] = fmaf(bflo(ra.z), okf, as[4]);  as[5] = fmaf(bfhi(ra.z), okf, as[5]);
    as[6] = fmaf(bflo(ra.w), okf, as[6]);  as[7] = fmaf(bfhi(ra.w), okf, as[7]);
    as[8] = fmaf(bflo(rb.x), okf, as[8]);  as[9] = fmaf(bfhi(rb.x), okf, as[9]);
    as[10] = fmaf(bflo(rb.y), okf, as[10]); as[11] = fmaf(bfhi(rb.y), okf, as[11]);
    as[12] = fmaf(bflo(rb.z), okf, as[12]); as[13] = fmaf(bfhi(rb.z), okf, as[13]);
    as[14] = fmaf(bflo(rb.w), okf, as[14]); as[15] = fmaf(bfhi(rb.w), okf, as[15]);
  }
#pragma unroll
  for (int off = 16; off >= 1; off >>= 1)
#pragma unroll
    for (int c = 0; c < 16; ++c) as[c] += __shfl_down(as[c], off, 64);
  // ---- node MLP on lanes l32<16 ----
  float aS[16], aR[16];
#pragma unroll
  for (int c = 0; c < 16; ++c) aS[c] = __shfl(as[c], half * 32, 64);
#pragma unroll
  for (int k = 0; k < 8; ++k) aR[k] = __shfl(ar[k], half * 32, 64);
#pragma unroll
  for (int k = 0; k < 8; ++k) aR[8 + k] = __shfl(ar[k], half * 32 + 1, 64);
  float nsv = nodesr[n];
  float pv = 0.f;
  if (l32 < 16) {
    int j = l32;
    float a1 = fmaf(nw1[j * 33], nsv, nb1_[j]);
#pragma unroll
    for (int k = 0; k < 16; ++k) a1 = fmaf(nw1[j * 33 + 1 + k], aS[k], a1);
#pragma unroll
    for (int k = 0; k < 16; ++k)
      a1 = fmaf(nw1[j * 33 + 17 + k], aR[k], a1);
    pv = nw2[j] * frelu(a1);
  }
#pragma unroll
  for (int off = 8; off >= 1; off >>= 1) pv += __shfl_down(pv, off, 64);
  if (l32 == 0) nodesw[n] = pv + nb2_[0];
}

// ---------------------------------------------------------------------------
// K7: edge MLP, 2 EDGES PER THREAD (best-measured form: 847 us build).
// Layer-2 chunked by 8 outputs with immediate 16 B stores. (256,4).
// ---------------------------------------------------------------------------
__global__ __launch_bounds__(256, 4) void k_edgeE(
    unsigned short* __restrict__ e, const unsigned int* __restrict__ srecv,
    const unsigned int* __restrict__ ssend32, const float* __restrict__ nodes,
    const float* __restrict__ w1, const float* __restrict__ b1,
    const float* __restrict__ w2, const float* __restrict__ b2) {
  int i0 = (blockIdx.x * blockDim.x + threadIdx.x) * 2;
  float ns[2], nr[2];
#pragma unroll
  for (int q = 0; q < 2; ++q) {
    ns[q] = nodes[ssend32[i0 + q]];
    nr[q] = nodes[srecv[i0 + q]];
  }
  unsigned int pk[2][8];
#pragma unroll
  for (int q = 0; q < 2; ++q) {
    const uint4* ep = (const uint4*)(e + (size_t)(i0 + q) * HID);
    uint4 ra = ep[0], rb = ep[1];
    pk[q][0] = ra.x; pk[q][1] = ra.y; pk[q][2] = ra.z; pk[q][3] = ra.w;
    pk[q][4] = rb.x; pk[q][5] = rb.y; pk[q][6] = rb.z; pk[q][7] = rb.w;
  }
  float h[2][16];
#pragma unroll
  for (int j = 0; j < 16; ++j) {
    float wA = w1[j * 18 + 16], wB = w1[j * 18 + 17], bb = b1[j];
#pragma unroll
    for (int q = 0; q < 2; ++q)
      h[q][j] = fmaf(wA, ns[q], fmaf(wB, nr[q], bb));
  }
#pragma unroll
  for (int kp = 0; kp < 8; ++kp) {
    float x0[2], x1[2];
#pragma unroll
    for (int q = 0; q < 2; ++q) {
      x0[q] = bflo(pk[q][kp]);
      x1[q] = bfhi(pk[q][kp]);
    }
#pragma unroll
    for (int j = 0; j < 16; ++j) {
      float wA = w1[j * 18 + 2 * kp], wB = w1[j * 18 + 2 * kp + 1];
#pragma unroll
      for (int q = 0; q < 2; ++q)
        h[q][j] = fmaf(wB, x1[q], fmaf(wA, x0[q], h[q][j]));
    }
  }
#pragma unroll
  for (int j = 0; j < 16; ++j)
#pragma unroll
    for (int q = 0; q < 2; ++q) h[q][j] = frelu(h[q][j]);
#pragma unroll
  for (int c0 = 0; c0 < 16; c0 += 8) {
    float y[2][8];
#pragma unroll
    for (int cc = 0; cc < 8; ++cc) {
      float bv = b2[c0 + cc];
#pragma unroll
      for (int q = 0; q < 2; ++q) y[q][cc] = bv;
    }
#pragma unroll
    for (int j = 0; j < 16; ++j) {
#pragma unroll
      for (int cc = 0; cc < 8; ++cc) {
        float wv = w2[(c0 + cc) * HID + j];
#pragma unroll
        for (int q = 0; q < 2; ++q) y[q][cc] = fmaf(wv, h[q][j], y[q][cc]);
      }
    }
#pragma unroll
    for (int q = 0; q < 2; ++q) {
      uint4 o = make_uint4(packbf(y[q][0], y[q][1]), packbf(y[q][2], y[q][3]),
                           packbf(y[q][4], y[q][5]), packbf(y[q][6], y[q][7]));
      *(uint4*)(e + (size_t)(i0 + q) * HID + c0) = o;
    }
  }
}

// ---------------------------------------------------------------------------
// K8: final — round-3 edge MLP + decoder, 2 EDGES PER THREAD (best-measured
// form). Writes delta only.
// ---------------------------------------------------------------------------
__global__ __launch_bounds__(256, 4) void k_final(
    const unsigned short* __restrict__ e, const unsigned int* __restrict__ srecv,
    const unsigned int* __restrict__ ssend32, const unsigned int* __restrict__ sorig,
    const float* __restrict__ nodes, const float* __restrict__ ew1,
    const float* __restrict__ eb1, const float* __restrict__ ew2,
    const float* __restrict__ eb2, const float* __restrict__ dw1,
    const float* __restrict__ db1, const float* __restrict__ dw2,
    const float* __restrict__ db2, const unsigned int* __restrict__ normbits,
    const float* __restrict__ alpha, float* __restrict__ out) {
  int i0 = (blockIdx.x * blockDim.x + threadIdx.x) * 2;
  float ns[2], nr[2];
#pragma unroll
  for (int q = 0; q < 2; ++q) {
    ns[q] = nodes[ssend32[i0 + q]];
    nr[q] = nodes[srecv[i0 + q]];
  }
  unsigned int pk[2][8];
#pragma unroll
  for (int q = 0; q < 2; ++q) {
    const uint4* ep = (const uint4*)(e + (size_t)(i0 + q) * HID);
    uint4 ra = ep[0], rb = ep[1];
    pk[q][0] = ra.x; pk[q][1] = ra.y; pk[q][2] = ra.z; pk[q][3] = ra.w;
    pk[q][4] = rb.x; pk[q][5] = rb.y; pk[q][6] = rb.z; pk[q][7] = rb.w;
  }
  float h[2][16];
#pragma unroll
  for (int j = 0; j < 16; ++j) {
    float wA = ew1[j * 18 + 16], wB = ew1[j * 18 + 17], bb = eb1[j];
#pragma unroll
    for (int q = 0; q < 2; ++q)
      h[q][j] = fmaf(wA, ns[q], fmaf(wB, nr[q], bb));
  }
#pragma unroll
  for (int kp = 0; kp < 8; ++kp) {
    float x0[2], x1[2];
#pragma unroll
    for (int q = 0; q < 2; ++q) {
      x0[q] = bflo(pk[q][kp]);
      x1[q] = bfhi(pk[q][kp]);
    }
#pragma unroll
    for (int j = 0; j < 16; ++j) {
      float wA = ew1[j * 18 + 2 * kp], wB = ew1[j * 18 + 2 * kp + 1];
#pragma unroll
      for (int q = 0; q < 2; ++q)
        h[q][j] = fmaf(wB, x1[q], fmaf(wA, x0[q], h[q][j]));
    }
  }
#pragma unroll
  for (int j = 0; j < 16; ++j)
#pragma unroll
    for (int q = 0; q < 2; ++q) h[q][j] = frelu(h[q][j]);
  float y[2][16];
#pragma unroll
  for (int c = 0; c < 16; ++c) {
    float bv = eb2[c];
#pragma unroll
    for (int q = 0; q < 2; ++q) y[q][c] = bv;
  }
#pragma unroll
  for (int j = 0; j < 16; ++j) {
#pragma unroll
    for (int c = 0; c < 16; ++c) {
      float wv = ew2[c * HID + j];
#pragma unroll
      for (int q = 0; q < 2; ++q) y[q][c] = fmaf(wv, h[q][j], y[q][c]);
    }
  }
  float d[2] = {db2[0], db2[0]};
#pragma unroll
  for (int j = 0; j < 16; ++j) {
    float a1[2] = {db1[j], db1[j]};
#pragma unroll
    for (int k = 0; k < 16; ++k) {
      float wv = dw1[j * HID + k];
#pragma unroll
      for (int q = 0; q < 2; ++q) a1[q] = fmaf(wv, y[q][k], a1[q]);
    }
    float wd = dw2[j];
#pragma unroll
    for (int q = 0; q < 2; ++q) d[q] = fmaf(wd, frelu(a1[q]), d[q]);
  }
  float alphaN = alpha[0] * __uint_as_float(*normbits);
#pragma unroll
  for (int q = 0; q < 2; ++q) out[sorig[i0 + q]] = alphaN * d[q];
}

// ---------------------------------------------------------------------------
// K9: residual add, fully coalesced: out[i] += edges_init[i]
// ---------------------------------------------------------------------------
__global__ __launch_bounds__(256) void k_resid(const float* __restrict__ edges,
                                               float* __restrict__ out) {
  int i = blockIdx.x * blockDim.x + threadIdx.x;
  out[i] += edges[i];
}

// ---------------------------------------------------------------------------
extern "C" void kernel_launch(void* const* d_in, const int* in_sizes, int n_in,
                              void* d_out, int out_size, void* d_ws,
                              size_t ws_size, hipStream_t stream) {
  const float* nodes0 = (const float*)d_in[0];
  const float* edges0 = (const float*)d_in[1];
  const int* senders = (const int*)d_in[2];
  const int* receivers = (const int*)d_in[3];
  const float* enc_w1 = (const float*)d_in[4];
  const float* enc_b1 = (const float*)d_in[5];
  const float* enc_w2 = (const float*)d_in[6];
  const float* enc_b2 = (const float*)d_in[7];
  const float* node_w1 = (const float*)d_in[8];
  const float* node_b1 = (const float*)d_in[9];
  const float* node_w2 = (const float*)d_in[10];
  const float* node_b2 = (const float*)d_in[11];
  const float* edge_w1 = (const float*)d_in[12];
  const float* edge_b1 = (const float*)d_in[13];
  const float* edge_w2 = (const float*)d_in[14];
  const float* edge_b2 = (const float*)d_in[15];
  const float* dec_w1 = (const float*)d_in[16];
  const float* dec_b1 = (const float*)d_in[17];
  const float* dec_w2 = (const float*)d_in[18];
  const float* dec_b2 = (const float*)d_in[19];
  const float* alpha = (const float*)d_in[20];

  // Workspace layout: ~162 MB (< proven 167.6 MB budget).
  char* ws = (char*)d_ws;
  unsigned short* e = (unsigned short*)ws;  // 3.2M x 32 B = 102.4 MB (sorted)
  char* p = ws + (size_t)N_EDGES * HID * 2;
  unsigned int* srecv = (unsigned int*)p;    p += (size_t)N_EDGES * 4;  // 12.8
  unsigned int* sorig = (unsigned int*)p;    p += (size_t)N_EDGES * 4;  // 12.8
  unsigned int* rlist = (unsigned int*)p;    p += (size_t)N_EDGES * 4;  // 12.8
  unsigned int* ssend32 = (unsigned int*)p;  p += (size_t)N_EDGES * 4;  // 12.8
  unsigned short* svalbf = (unsigned short*)p; p += (size_t)N_EDGES * 2;  // 6.4
  int* soff = (int*)p;                       p += (size_t)(N_NODES + 16) * 4;
  int* roff = (int*)p;                       p += (size_t)(N_NODES + 16) * 4;
  float* nbA = (float*)p;                    p += (size_t)N_NODES * 4;
  float* nbB = (float*)p;                    p += (size_t)N_NODES * 4;
  unsigned int* normbits = (unsigned int*)p; p += 64;
  int* gcnt = (int*)p;                       p += NB * 4;
  int* gcnt2 = (int*)p;                      p += NB * 4;
  // build staging aliases e (dead until k_encode):
  unsigned int* pM = (unsigned int*)ws;
  float* pV = (float*)(ws + (size_t)NB * SCAP * 4);
  unsigned int* pO = (unsigned int*)(ws + (size_t)NB * SCAP * 8);
  unsigned int* rpA = (unsigned int*)(ws + (size_t)NB * SCAP * 12);

  const int ngrid = 12500;   // 2 nodes/wave x 4 waves/block -> 100000 nodes
  const int egrid = N_EDGES / BLK;        // 12500
  const int egrid2 = N_EDGES / (BLK * 2); // 6250 (2 edges/thread)

  hipMemsetAsync(normbits, 0, 64 + 2 * NB * 4, stream);  // norm + gcnt + gcnt2
  k_norm<<<512, BLK, 0, stream>>>(edges0, normbits);
  k_split<<<256, 1024, 0, stream>>>(senders, receivers, edges0, gcnt, pM, pV, pO);
  k_bsort1<<<NB, 1024, 0, stream>>>(pM, pV, pO, gcnt, srecv, sorig, svalbf,
                                    ssend32, soff);
  k_rsplit<<<256, 1024, 0, stream>>>(srecv, gcnt2, rpA);
  k_rsort<<<NB, 1024, 0, stream>>>(rpA, gcnt2, rlist, roff);
  k_encode<<<egrid, BLK, 0, stream>>>(svalbf, enc_w1, enc_b1, enc_w2, enc_b2,
                                      normbits, e);  // clobbers staging
  // round 1
  k_aggN<<<ngrid, BLK, 0, stream>>>(e, roff, rlist, soff, nodes0, node_w1,
                                    node_b1, node_w2, node_b2, nbA);
  k_edgeE<<<egrid2, BLK, 0, stream>>>(e, srecv, ssend32, nbA, edge_w1,
                                      edge_b1, edge_w2, edge_b2);
  // round 2
  k_aggN<<<ngrid, BLK, 0, stream>>>(e, roff, rlist, soff, nbA, node_w1,
                                    node_b1, node_w2, node_b2, nbB);
  k_edgeE<<<egrid2, BLK, 0, stream>>>(e, srecv, ssend32, nbB, edge_w1,
                                      edge_b1, edge_w2, edge_b2);
  // round 3
  k_aggN<<<ngrid, BLK, 0, stream>>>(e, roff, rlist, soff, nbB, node_w1,
                                    node_b1, node_w2, node_b2, nbA);
  // final: e3 = edgeMLP(e2, nbA) -> decoder -> delta; then residual add
  k_final<<<egrid2, BLK, 0, stream>>>(e, srecv, ssend32, sorig, nbA, edge_w1,
                                      edge_b1, edge_w2, edge_b2, dec_w1,
                                      dec_b1, dec_w2, dec_b2, normbits, alpha,
                                      (float*)d_out);
  k_resid<<<egrid, BLK, 0, stream>>>(edges0, (float*)d_out);
}